// Round 2
// baseline (1625.078 us; speedup 1.0000x reference)
//
#include <hip/hip_runtime.h>
#include <hip/hip_bf16.h>

#define NNODES 50000
#define NEDGES 150000
#define DFEAT  512
#define HID    512
#define NCLS   47
#define CHUNK  64
#define NCHUNK (HID / CHUNK)

typedef __hip_bfloat16 bf16;

// ---------------- dtype detection ----------------
// flags[0] = 1 if float arrays are bf16 (else fp32)
// flags[1] = 1 if edge_index is int64 (else int32)
__global__ void k_detect(const void* x, const void* ei, int* flags) {
    if (blockIdx.x != 0 || threadIdx.x != 0) return;
    const unsigned short* xs = (const unsigned short*)x;
    int cnt = 0;
    for (int i = 0; i < 256; ++i) {
        // low half of 32-bit word i: if data is bf16 this is a real value
        // ~N(0,1); if fp32 it is random mantissa bits.
        unsigned int e = (xs[2 * i] >> 7) & 0xFF;
        if (e >= 117 && e <= 130) cnt++;  // |v| in ~(2^-10, 2^4)
    }
    flags[0] = (cnt > 128) ? 1 : 0;
    const int* w = (const int*)ei;
    int ornz = 0;
    for (int i = 1; i < 256; i += 2) ornz |= w[i];  // high words of int64 all 0
    flags[1] = (ornz == 0) ? 1 : 0;
}

__device__ __forceinline__ int eidx(const void* ei, int half, int e, int is64) {
    if (is64) return (int)((const long long*)ei)[(size_t)half * NEDGES + e];
    return ((const int*)ei)[half * NEDGES + e];
}

// ---------------- utility ----------------
__global__ void k_zero32(unsigned int* p, size_t n) {
    size_t i = (size_t)blockIdx.x * blockDim.x + threadIdx.x;
    if (i < n) p[i] = 0u;
}

__global__ void k_cvt(const void* src, float* dst, int n, const int* flags) {
    int i = blockIdx.x * blockDim.x + threadIdx.x;
    if (i >= n) return;
    dst[i] = flags[0] ? __bfloat162float(((const bf16*)src)[i]) : ((const float*)src)[i];
}

// ---------------- graph structure ----------------
__global__ void k_count(const void* ei, int* cnt, const int* flags) {
    int e = blockIdx.x * blockDim.x + threadIdx.x;
    if (e >= NEDGES) return;
    atomicAdd(&cnt[eidx(ei, 1, e, flags[1])], 1);
}

__global__ void k_dinv(const int* cnt, float* dinv) {
    int i = blockIdx.x * blockDim.x + threadIdx.x;
    if (i < NNODES) dinv[i] = rsqrtf(1.0f + (float)cnt[i]);
}

// single-block inclusive scan -> rowptr (exclusive) + cursor init
__global__ __launch_bounds__(1024) void k_scan(const int* cnt, int* rowptr, int* cursor) {
    __shared__ int tile[1024];
    __shared__ int carry_s;
    int tid = threadIdx.x;
    if (tid == 0) carry_s = 0;
    __syncthreads();
    for (int base = 0; base < NNODES; base += 1024) {
        int i = base + tid;
        int v = (i < NNODES) ? cnt[i] : 0;
        tile[tid] = v;
        __syncthreads();
        for (int off = 1; off < 1024; off <<= 1) {
            int t = (tid >= off) ? tile[tid - off] : 0;
            __syncthreads();
            tile[tid] += t;
            __syncthreads();
        }
        int incl = tile[tid] + carry_s;
        if (i < NNODES) {
            rowptr[i + 1] = incl;
            cursor[i] = incl - v;  // exclusive prefix
        }
        __syncthreads();
        if (tid == 1023) carry_s = incl;
        __syncthreads();
    }
    if (tid == 0) rowptr[0] = 0;
}

__global__ void k_fill(const void* ei, int* cursor, int* csr_src, const int* flags) {
    int e = blockIdx.x * blockDim.x + threadIdx.x;
    if (e >= NEDGES) return;
    int is64 = flags[1];
    int v = eidx(ei, 1, e, is64);
    int u = eidx(ei, 0, e, is64);
    int pos = atomicAdd(&cursor[v], 1);
    csr_src[pos] = u;
}

// ---------------- GEMM1 chunk: h1c[50000, 64] = x @ W1[:, c0:c0+64] ----------------
__global__ __launch_bounds__(256) void k_gemm1(const void* A, const float* W,
                                               bf16* h1c, int c0, const int* flags) {
    __shared__ float As[16][65];
    __shared__ float Bs[16][65];
    int isb = flags[0];
    int tx = threadIdx.x & 15, ty = threadIdx.x >> 4;
    int row0 = blockIdx.x * 64;
    float acc[4][4] = {};
    for (int k0 = 0; k0 < DFEAT; k0 += 16) {
        for (int i = threadIdx.x; i < 64 * 16; i += 256) {
            int m = i >> 4, k = i & 15;
            int gm = row0 + m;
            float v = 0.0f;
            if (gm < NNODES) {
                size_t idx = (size_t)gm * DFEAT + k0 + k;
                v = isb ? __bfloat162float(((const bf16*)A)[idx]) : ((const float*)A)[idx];
            }
            As[k][m] = v;
        }
        for (int i = threadIdx.x; i < 16 * 64; i += 256) {
            int k = i >> 6, n = i & 63;
            Bs[k][n] = W[(size_t)(k0 + k) * HID + c0 + n];
        }
        __syncthreads();
#pragma unroll
        for (int kk = 0; kk < 16; ++kk) {
            float a[4], b[4];
#pragma unroll
            for (int i = 0; i < 4; i++) a[i] = As[kk][ty * 4 + i];
#pragma unroll
            for (int j = 0; j < 4; j++) b[j] = Bs[kk][tx * 4 + j];
#pragma unroll
            for (int i = 0; i < 4; i++)
#pragma unroll
                for (int j = 0; j < 4; j++) acc[i][j] += a[i] * b[j];
        }
        __syncthreads();
    }
#pragma unroll
    for (int i = 0; i < 4; i++) {
        int gm = row0 + ty * 4 + i;
        if (gm < NNODES) {
#pragma unroll
            for (int j = 0; j < 4; j++)
                h1c[(size_t)gm * CHUNK + tx * 4 + j] = __float2bfloat16(acc[i][j]);
        }
    }
}

// ---------------- layer1 aggregation (CSR gather) + bias + relu ----------------
__global__ __launch_bounds__(256) void k_agg1(const bf16* __restrict__ h1c,
                                              const int* __restrict__ rowptr,
                                              const int* __restrict__ csr_src,
                                              const float* __restrict__ dinv,
                                              const float* __restrict__ b1c, int c0,
                                              bf16* __restrict__ a1c) {
    int v = blockIdx.x * 4 + (threadIdx.x >> 6);
    int d = threadIdx.x & 63;
    if (v >= NNODES) return;
    float dv = dinv[v];
    float acc = dv * dv * __bfloat162float(h1c[(size_t)v * CHUNK + d]);
    int pend = rowptr[v + 1];
    for (int p = rowptr[v]; p < pend; ++p) {
        int u = csr_src[p];
        acc += dinv[u] * dv * __bfloat162float(h1c[(size_t)u * CHUNK + d]);
    }
    float r = acc + b1c[c0 + d];
    a1c[(size_t)v * CHUNK + d] = __float2bfloat16(r > 0.0f ? r : 0.0f);
}

// ---------------- GEMM2 chunk: h2 += a1c @ W2[c0:c0+64, :] ----------------
__global__ __launch_bounds__(256) void k_gemm2(const bf16* __restrict__ a1c,
                                               const float* __restrict__ W2c, int c0,
                                               float* __restrict__ h2) {
    __shared__ float W2s[CHUNK * NCLS];
    for (int i = threadIdx.x; i < CHUNK * NCLS; i += 256) {
        int k = i / NCLS, j = i % NCLS;
        W2s[i] = W2c[(size_t)(c0 + k) * NCLS + j];
    }
    __syncthreads();
    const size_t total = (size_t)NNODES * NCLS;
    for (size_t idx = (size_t)blockIdx.x * 256 + threadIdx.x; idx < total;
         idx += (size_t)gridDim.x * 256) {
        int v = (int)(idx / NCLS), j = (int)(idx % NCLS);
        const bf16* a = a1c + (size_t)v * CHUNK;
        float s = 0.0f;
#pragma unroll
        for (int k = 0; k < CHUNK; ++k) s += __bfloat162float(a[k]) * W2s[k * NCLS + j];
        h2[idx] += s;
    }
}

// ---------------- layer2 aggregation + bias -> out (bf16 or fp32) ----------------
__global__ __launch_bounds__(256) void k_agg2(const float* __restrict__ h2,
                                              const int* __restrict__ rowptr,
                                              const int* __restrict__ csr_src,
                                              const float* __restrict__ dinv,
                                              const float* __restrict__ b2c,
                                              void* out, const int* flags) {
    int v = blockIdx.x * 4 + (threadIdx.x >> 6);
    int d = threadIdx.x & 63;
    if (v >= NNODES || d >= NCLS) return;
    float dv = dinv[v];
    float acc = dv * dv * h2[(size_t)v * NCLS + d];
    int pend = rowptr[v + 1];
    for (int p = rowptr[v]; p < pend; ++p) {
        int u = csr_src[p];
        acc += dinv[u] * dv * h2[(size_t)u * NCLS + d];
    }
    acc += b2c[d];
    size_t o = (size_t)v * NCLS + d;
    if (flags[0]) ((bf16*)out)[o] = __float2bfloat16(acc);
    else          ((float*)out)[o] = acc;
}

extern "C" void kernel_launch(void* const* d_in, const int* in_sizes, int n_in,
                              void* d_out, int out_size, void* d_ws, size_t ws_size,
                              hipStream_t stream) {
    const void* x  = d_in[0];
    const void* ei = d_in[1];
    const void* W1 = d_in[2];
    const void* b1 = d_in[3];
    const void* W2 = d_in[4];
    const void* b2 = d_in[5];

    // ---- workspace layout (~25 MB) ----
    char* base = (char*)d_ws;
    auto alloc = [&](size_t bytes) -> char* {
        char* p = base;
        base += (bytes + 255) & ~(size_t)255;
        return p;
    };
    int*   flags  = (int*)alloc(64);
    int*   cnt    = (int*)alloc(sizeof(int) * NNODES);
    int*   rowptr = (int*)alloc(sizeof(int) * (NNODES + 1));
    int*   cursor = (int*)alloc(sizeof(int) * NNODES);
    int*   csr    = (int*)alloc(sizeof(int) * NEDGES);
    float* dinv   = (float*)alloc(sizeof(float) * NNODES);
    float* Wc1    = (float*)alloc(sizeof(float) * DFEAT * HID);
    float* b1c    = (float*)alloc(sizeof(float) * HID);
    float* W2c    = (float*)alloc(sizeof(float) * HID * NCLS);
    float* b2c    = (float*)alloc(sizeof(float) * 64);
    bf16*  h1c    = (bf16*)alloc(sizeof(bf16) * (size_t)NNODES * CHUNK);
    bf16*  a1c    = (bf16*)alloc(sizeof(bf16) * (size_t)NNODES * CHUNK);
    float* h2     = (float*)alloc(sizeof(float) * (size_t)NNODES * NCLS);

    // ---- dtype detection ----
    k_detect<<<1, 64, 0, stream>>>(x, ei, flags);

    // ---- zero cnt and h2 ----
    k_zero32<<<(NNODES + 255) / 256, 256, 0, stream>>>((unsigned int*)cnt, NNODES);
    {
        size_t n = (size_t)NNODES * NCLS;
        k_zero32<<<(int)((n + 255) / 256), 256, 0, stream>>>((unsigned int*)h2, n);
    }

    // ---- canonicalize weights to fp32 ----
    k_cvt<<<(DFEAT * HID + 255) / 256, 256, 0, stream>>>(W1, Wc1, DFEAT * HID, flags);
    k_cvt<<<(HID + 255) / 256, 256, 0, stream>>>(b1, b1c, HID, flags);
    k_cvt<<<(HID * NCLS + 255) / 256, 256, 0, stream>>>(W2, W2c, HID * NCLS, flags);
    k_cvt<<<1, 64, 0, stream>>>(b2, b2c, NCLS, flags);

    // ---- graph: degree, dinv, CSR ----
    k_count<<<(NEDGES + 255) / 256, 256, 0, stream>>>(ei, cnt, flags);
    k_dinv<<<(NNODES + 255) / 256, 256, 0, stream>>>(cnt, dinv);
    k_scan<<<1, 1024, 0, stream>>>(cnt, rowptr, cursor);
    k_fill<<<(NEDGES + 255) / 256, 256, 0, stream>>>(ei, cursor, csr, flags);

    // ---- layers, chunked over HID columns ----
    const int rowblocks = (NNODES + 63) / 64;  // 782
    for (int c = 0; c < NCHUNK; ++c) {
        int c0 = c * CHUNK;
        k_gemm1<<<rowblocks, 256, 0, stream>>>(x, Wc1, h1c, c0, flags);
        k_agg1<<<(NNODES + 3) / 4, 256, 0, stream>>>(h1c, rowptr, csr, dinv, b1c, c0, a1c);
        k_gemm2<<<2048, 256, 0, stream>>>(a1c, W2c, c0, h2);
    }

    // ---- final aggregation + bias -> out ----
    k_agg2<<<(NNODES + 3) / 4, 256, 0, stream>>>(h2, rowptr, csr, dinv, b2c, d_out, flags);
}

// Round 3
// 782.081 us; speedup vs baseline: 2.0779x; 2.0779x over previous
//
#include <hip/hip_runtime.h>
#include <hip/hip_bf16.h>

#define NNODES 50000
#define NEDGES 150000
#define DFEAT  512
#define HID    512
#define NCLS   47

typedef __hip_bfloat16 bf16;
typedef __attribute__((ext_vector_type(8))) short short8;
typedef __attribute__((ext_vector_type(4))) float float4v;

typedef const __attribute__((address_space(1))) unsigned int* gas_t;
typedef __attribute__((address_space(3))) unsigned int* las_t;
__device__ __forceinline__ void load_lds16(const void* g, void* l) {
    __builtin_amdgcn_global_load_lds((gas_t)g, (las_t)l, 16, 0, 0);
}

// ---------------- dtype detection ----------------
__global__ void k_detect(const void* x, const void* ei, int* flags) {
    if (blockIdx.x != 0 || threadIdx.x != 0) return;
    const unsigned short* xs = (const unsigned short*)x;
    int cnt = 0;
    for (int i = 0; i < 256; ++i) {
        unsigned int e = (xs[2 * i] >> 7) & 0xFF;
        if (e >= 117 && e <= 130) cnt++;
    }
    flags[0] = (cnt > 128) ? 1 : 0;
    const int* w = (const int*)ei;
    int ornz = 0;
    for (int i = 1; i < 256; i += 2) ornz |= w[i];
    flags[1] = (ornz == 0) ? 1 : 0;
}

__device__ __forceinline__ int eidx(const void* ei, int half, int e, int is64) {
    if (is64) return (int)((const long long*)ei)[(size_t)half * NEDGES + e];
    return ((const int*)ei)[half * NEDGES + e];
}

// ---------------- utility ----------------
__global__ void k_zero32(unsigned int* p, size_t n) {
    size_t i = (size_t)blockIdx.x * blockDim.x + threadIdx.x;
    if (i < n) p[i] = 0u;
}

__global__ void k_cvt(const void* src, float* dst, int n, const int* flags) {
    int i = blockIdx.x * blockDim.x + threadIdx.x;
    if (i >= n) return;
    dst[i] = flags[0] ? __bfloat162float(((const bf16*)src)[i]) : ((const float*)src)[i];
}

// W1 [K=512][N=512] -> W1T bf16 [N][K]
__global__ void k_cvt_w1t(const void* W1, bf16* W1T, const int* flags) {
    int i = blockIdx.x * blockDim.x + threadIdx.x;
    if (i >= DFEAT * HID) return;
    int k = i / HID, n = i % HID;
    float v = flags[0] ? __bfloat162float(((const bf16*)W1)[i]) : ((const float*)W1)[i];
    W1T[(size_t)n * DFEAT + k] = __float2bfloat16(v);
}

// ---------------- graph structure ----------------
__global__ void k_count(const void* ei, int* cnt, const int* flags) {
    int e = blockIdx.x * blockDim.x + threadIdx.x;
    if (e >= NEDGES) return;
    atomicAdd(&cnt[eidx(ei, 1, e, flags[1])], 1);
}

__global__ void k_dinv(const int* cnt, float* dinv) {
    int i = blockIdx.x * blockDim.x + threadIdx.x;
    if (i < NNODES) dinv[i] = rsqrtf(1.0f + (float)cnt[i]);
}

__global__ __launch_bounds__(1024) void k_scan(const int* cnt, int* rowptr, int* cursor) {
    __shared__ int tile[1024];
    __shared__ int carry_s;
    int tid = threadIdx.x;
    if (tid == 0) carry_s = 0;
    __syncthreads();
    for (int base = 0; base < NNODES; base += 1024) {
        int i = base + tid;
        int v = (i < NNODES) ? cnt[i] : 0;
        tile[tid] = v;
        __syncthreads();
        for (int off = 1; off < 1024; off <<= 1) {
            int t = (tid >= off) ? tile[tid - off] : 0;
            __syncthreads();
            tile[tid] += t;
            __syncthreads();
        }
        int incl = tile[tid] + carry_s;
        if (i < NNODES) {
            rowptr[i + 1] = incl;
            cursor[i] = incl - v;
        }
        __syncthreads();
        if (tid == 1023) carry_s = incl;
        __syncthreads();
    }
    if (tid == 0) rowptr[0] = 0;
}

__global__ void k_fill(const void* ei, int* cursor, int* csr_src, const int* flags) {
    int e = blockIdx.x * blockDim.x + threadIdx.x;
    if (e >= NEDGES) return;
    int is64 = flags[1];
    int v = eidx(ei, 1, e, is64);
    int u = eidx(ei, 0, e, is64);
    int pos = atomicAdd(&cursor[v], 1);
    csr_src[pos] = u;
}

// ---------------- GEMM1 MFMA: h1c[:, 0:C] = x @ W1[:, c0:c0+C] ----------------
// BM=128, BN=64 (grid.y covers C/64), BK=64, 256 threads = 4 waves, each wave 32x64.
__global__ __launch_bounds__(256) void k_gemm1_mfma(
    const void* __restrict__ X, const bf16* __restrict__ W1T,
    bf16* __restrict__ h1c, int c0, int C, const int* __restrict__ flags) {
    __shared__ bf16 As[128 * 64];
    __shared__ bf16 Bs[64 * 64];
    const int tid = threadIdx.x;
    const int wave = tid >> 6, lane = tid & 63;
    const int row0 = blockIdx.x * 128;
    const int gc0 = c0 + blockIdx.y * 64;  // global col base in HID
    const int isb = flags[0];

    float4v acc[2][4];
#pragma unroll
    for (int i = 0; i < 2; i++)
#pragma unroll
        for (int j = 0; j < 4; j++) acc[i][j] = (float4v){0.f, 0.f, 0.f, 0.f};

    const int rbase = wave * 32;
    const int fl_row = lane & 15;
    const int fl_k8 = (lane >> 4) * 8;

    for (int k0 = 0; k0 < DFEAT; k0 += 64) {
        __syncthreads();
        if (isb) {
            const bf16* xb = (const bf16*)X;
#pragma unroll
            for (int i = 0; i < 4; ++i) {
                int r = i * 32 + wave * 8;                  // wave-uniform LDS row base
                int gr = row0 + r + (lane >> 3);
                if (gr >= NNODES) gr = NNODES - 1;
                load_lds16(xb + (size_t)gr * DFEAT + k0 + (lane & 7) * 8, &As[r * 64]);
            }
        } else {
            const float* xf = (const float*)X;
            for (int i = tid; i < 128 * 64; i += 256) {
                int r = i >> 6, c = i & 63;
                int gr = row0 + r;
                if (gr >= NNODES) gr = NNODES - 1;
                As[i] = __float2bfloat16(xf[(size_t)gr * DFEAT + k0 + c]);
            }
        }
#pragma unroll
        for (int i = 0; i < 2; ++i) {
            int r = i * 32 + wave * 8;                      // col-within-64 base
            int gn = gc0 + r + (lane >> 3);
            load_lds16(W1T + (size_t)gn * DFEAT + k0 + (lane & 7) * 8, &Bs[r * 64]);
        }
        __syncthreads();
#pragma unroll
        for (int ki = 0; ki < 64; ki += 32) {
            short8 a[2], b[4];
#pragma unroll
            for (int i = 0; i < 2; i++)
                a[i] = *(const short8*)&As[(rbase + i * 16 + fl_row) * 64 + ki + fl_k8];
#pragma unroll
            for (int j = 0; j < 4; j++)
                b[j] = *(const short8*)&Bs[(j * 16 + fl_row) * 64 + ki + fl_k8];
#pragma unroll
            for (int i = 0; i < 2; i++)
#pragma unroll
                for (int j = 0; j < 4; j++)
                    acc[i][j] = __builtin_amdgcn_mfma_f32_16x16x32_bf16(a[i], b[j], acc[i][j], 0, 0, 0);
        }
    }
    const int ccol = blockIdx.y * 64;
#pragma unroll
    for (int i = 0; i < 2; i++) {
#pragma unroll
        for (int r = 0; r < 4; r++) {
            int grow = row0 + rbase + i * 16 + (lane >> 4) * 4 + r;
            if (grow < NNODES) {
#pragma unroll
                for (int j = 0; j < 4; j++)
                    h1c[(size_t)grow * C + ccol + j * 16 + (lane & 15)] =
                        __float2bfloat16(acc[i][j][r]);
            }
        }
    }
}

// ---------------- layer1 aggregation (CSR gather) + bias + relu ----------------
__global__ __launch_bounds__(256) void k_agg1(const bf16* __restrict__ h1c,
                                              const int* __restrict__ rowptr,
                                              const int* __restrict__ csr_src,
                                              const float* __restrict__ dinv,
                                              const float* __restrict__ b1c, int c0, int C,
                                              bf16* __restrict__ a1c) {
    int v = blockIdx.x * 4 + (threadIdx.x >> 6);
    int d = blockIdx.y * 64 + (threadIdx.x & 63);
    if (v >= NNODES) return;
    float dv = dinv[v];
    float acc = dv * dv * __bfloat162float(h1c[(size_t)v * C + d]);
    int pend = rowptr[v + 1];
    for (int p = rowptr[v]; p < pend; ++p) {
        int u = csr_src[p];
        acc += dinv[u] * dv * __bfloat162float(h1c[(size_t)u * C + d]);
    }
    float r = acc + b1c[c0 + d];
    a1c[(size_t)v * C + d] = __float2bfloat16(r > 0.0f ? r : 0.0f);
}

// ---------------- GEMM2 sub-chunk: h2 += a1c[:, s:s+64] @ W2[kg:kg+64, :] ----------------
__global__ __launch_bounds__(256) void k_gemm2(const bf16* __restrict__ a1c, int C, int s,
                                               const float* __restrict__ W2c, int kg,
                                               float* __restrict__ h2) {
    __shared__ float W2s[64 * NCLS];
    for (int i = threadIdx.x; i < 64 * NCLS; i += 256) {
        int k = i / NCLS, j = i % NCLS;
        W2s[i] = W2c[(size_t)(kg + k) * NCLS + j];
    }
    __syncthreads();
    const size_t total = (size_t)NNODES * NCLS;
    for (size_t idx = (size_t)blockIdx.x * 256 + threadIdx.x; idx < total;
         idx += (size_t)gridDim.x * 256) {
        int v = (int)(idx / NCLS), j = (int)(idx % NCLS);
        const bf16* a = a1c + (size_t)v * C + s;
        float sum = 0.0f;
#pragma unroll
        for (int k = 0; k < 64; ++k) sum += __bfloat162float(a[k]) * W2s[k * NCLS + j];
        h2[idx] += sum;
    }
}

// ---------------- layer2 aggregation + bias -> out ----------------
__global__ __launch_bounds__(256) void k_agg2(const float* __restrict__ h2,
                                              const int* __restrict__ rowptr,
                                              const int* __restrict__ csr_src,
                                              const float* __restrict__ dinv,
                                              const float* __restrict__ b2c,
                                              void* out, const int* flags) {
    int v = blockIdx.x * 4 + (threadIdx.x >> 6);
    int d = threadIdx.x & 63;
    if (v >= NNODES || d >= NCLS) return;
    float dv = dinv[v];
    float acc = dv * dv * h2[(size_t)v * NCLS + d];
    int pend = rowptr[v + 1];
    for (int p = rowptr[v]; p < pend; ++p) {
        int u = csr_src[p];
        acc += dinv[u] * dv * h2[(size_t)u * NCLS + d];
    }
    acc += b2c[d];
    size_t o = (size_t)v * NCLS + d;
    if (flags[0]) ((bf16*)out)[o] = __float2bfloat16(acc);
    else          ((float*)out)[o] = acc;
}

extern "C" void kernel_launch(void* const* d_in, const int* in_sizes, int n_in,
                              void* d_out, int out_size, void* d_ws, size_t ws_size,
                              hipStream_t stream) {
    const void* x  = d_in[0];
    const void* ei = d_in[1];
    const void* W1 = d_in[2];
    const void* b1 = d_in[3];
    const void* W2 = d_in[4];
    const void* b2 = d_in[5];

    char* base = (char*)d_ws;
    auto alloc = [&](size_t bytes) -> char* {
        char* p = base;
        base += (bytes + 255) & ~(size_t)255;
        return p;
    };
    int*   flags  = (int*)alloc(64);
    int*   cnt    = (int*)alloc(sizeof(int) * NNODES);
    int*   rowptr = (int*)alloc(sizeof(int) * (NNODES + 1));
    int*   cursor = (int*)alloc(sizeof(int) * NNODES);
    int*   csr    = (int*)alloc(sizeof(int) * NEDGES);
    float* dinv   = (float*)alloc(sizeof(float) * NNODES);
    bf16*  W1T    = (bf16*)alloc(sizeof(bf16) * DFEAT * HID);
    float* b1c    = (float*)alloc(sizeof(float) * HID);
    float* W2c    = (float*)alloc(sizeof(float) * HID * NCLS);
    float* b2c    = (float*)alloc(sizeof(float) * 64);
    float* h2     = (float*)alloc(sizeof(float) * (size_t)NNODES * NCLS);

    // runtime chunk-width selection (ws_size constant across calls -> graph-safe)
    size_t used = (size_t)(base - (char*)d_ws);
    size_t rem = (ws_size > used) ? ws_size - used : 0;
    int C = 64;
    if (rem >= (size_t)200000 * 256 + 1024) C = 256;
    else if (rem >= (size_t)200000 * 128 + 1024) C = 128;
    bf16* h1c = (bf16*)alloc(sizeof(bf16) * (size_t)NNODES * C);
    bf16* a1c = (bf16*)alloc(sizeof(bf16) * (size_t)NNODES * C);

    k_detect<<<1, 64, 0, stream>>>(x, ei, flags);

    k_zero32<<<(NNODES + 255) / 256, 256, 0, stream>>>((unsigned int*)cnt, NNODES);
    {
        size_t n = (size_t)NNODES * NCLS;
        k_zero32<<<(int)((n + 255) / 256), 256, 0, stream>>>((unsigned int*)h2, n);
    }

    k_cvt_w1t<<<(DFEAT * HID + 255) / 256, 256, 0, stream>>>(W1, W1T, flags);
    k_cvt<<<(HID + 255) / 256, 256, 0, stream>>>(b1, b1c, HID, flags);
    k_cvt<<<(HID * NCLS + 255) / 256, 256, 0, stream>>>(W2, W2c, HID * NCLS, flags);
    k_cvt<<<1, 64, 0, stream>>>(b2, b2c, NCLS, flags);

    k_count<<<(NEDGES + 255) / 256, 256, 0, stream>>>(ei, cnt, flags);
    k_dinv<<<(NNODES + 255) / 256, 256, 0, stream>>>(cnt, dinv);
    k_scan<<<1, 1024, 0, stream>>>(cnt, rowptr, cursor);
    k_fill<<<(NEDGES + 255) / 256, 256, 0, stream>>>(ei, cursor, csr, flags);

    const int rowblocks = (NNODES + 127) / 128;  // 391
    for (int c0 = 0; c0 < HID; c0 += C) {
        dim3 g1(rowblocks, C / 64);
        k_gemm1_mfma<<<g1, 256, 0, stream>>>(x, W1T, h1c, c0, C, flags);
        dim3 ga((NNODES + 3) / 4, C / 64);
        k_agg1<<<ga, 256, 0, stream>>>(h1c, rowptr, csr, dinv, b1c, c0, C, a1c);
        for (int s = 0; s < C; s += 64)
            k_gemm2<<<2048, 256, 0, stream>>>(a1c, C, s, W2c, c0 + s, h2);
    }

    k_agg2<<<(NNODES + 3) / 4, 256, 0, stream>>>(h2, rowptr, csr, dinv, b2c, d_out, flags);
}

// Round 4
// 438.612 us; speedup vs baseline: 3.7050x; 1.7831x over previous
//
#include <hip/hip_runtime.h>
#include <hip/hip_bf16.h>

#define NNODES 50000
#define NEDGES 150000
#define DFEAT  512
#define HID    512
#define NCLS   47

typedef __hip_bfloat16 bf16;
typedef __attribute__((ext_vector_type(8))) short short8;
typedef __attribute__((ext_vector_type(4))) float float4v;

typedef const __attribute__((address_space(1))) unsigned int* gas_t;
typedef __attribute__((address_space(3))) unsigned int* las_t;
__device__ __forceinline__ void load_lds16(const void* g, void* l) {
    __builtin_amdgcn_global_load_lds((gas_t)g, (las_t)l, 16, 0, 0);
}

__device__ __forceinline__ float bfbits_lo(unsigned int w) {
    return __uint_as_float((w & 0xFFFFu) << 16);
}
__device__ __forceinline__ float bfbits_hi(unsigned int w) {
    return __uint_as_float(w & 0xFFFF0000u);
}

// ---------------- dtype detection ----------------
__global__ void k_detect(const void* x, const void* ei, int* flags) {
    if (blockIdx.x != 0 || threadIdx.x != 0) return;
    const unsigned short* xs = (const unsigned short*)x;
    int cnt = 0;
    for (int i = 0; i < 256; ++i) {
        unsigned int e = (xs[2 * i] >> 7) & 0xFF;
        if (e >= 117 && e <= 130) cnt++;
    }
    flags[0] = (cnt > 128) ? 1 : 0;
    const int* w = (const int*)ei;
    int ornz = 0;
    for (int i = 1; i < 256; i += 2) ornz |= w[i];
    flags[1] = (ornz == 0) ? 1 : 0;
}

__device__ __forceinline__ int eidx(const void* ei, int half, int e, int is64) {
    if (is64) return (int)((const long long*)ei)[(size_t)half * NEDGES + e];
    return ((const int*)ei)[half * NEDGES + e];
}

// ---------------- utility ----------------
__global__ void k_zero32(unsigned int* p, size_t n) {
    size_t i = (size_t)blockIdx.x * blockDim.x + threadIdx.x;
    if (i < n) p[i] = 0u;
}

__global__ void k_cvt(const void* src, float* dst, int n, const int* flags) {
    int i = blockIdx.x * blockDim.x + threadIdx.x;
    if (i >= n) return;
    dst[i] = flags[0] ? __bfloat162float(((const bf16*)src)[i]) : ((const float*)src)[i];
}

// W1 [K=512][N=512] -> W1T bf16 [N][K]
__global__ void k_cvt_w1t(const void* W1, bf16* W1T, const int* flags) {
    int i = blockIdx.x * blockDim.x + threadIdx.x;
    if (i >= DFEAT * HID) return;
    int k = i / HID, n = i % HID;
    float v = flags[0] ? __bfloat162float(((const bf16*)W1)[i]) : ((const float*)W1)[i];
    W1T[(size_t)n * DFEAT + k] = __float2bfloat16(v);
}

// W2 [K=512][N=47] -> W2T bf16 [64][512] zero-padded
__global__ void k_cvt_w2t(const void* W2, bf16* W2T, const int* flags) {
    int i = blockIdx.x * blockDim.x + threadIdx.x;
    if (i >= 64 * HID) return;
    int n = i / HID, k = i % HID;
    float v = 0.0f;
    if (n < NCLS) {
        size_t idx = (size_t)k * NCLS + n;
        v = flags[0] ? __bfloat162float(((const bf16*)W2)[idx]) : ((const float*)W2)[idx];
    }
    W2T[(size_t)n * HID + k] = __float2bfloat16(v);
}

// ---------------- graph structure ----------------
__global__ void k_count(const void* ei, int* cnt, const int* flags) {
    int e = blockIdx.x * blockDim.x + threadIdx.x;
    if (e >= NEDGES) return;
    atomicAdd(&cnt[eidx(ei, 1, e, flags[1])], 1);
}

__global__ void k_dinv(const int* cnt, float* dinv) {
    int i = blockIdx.x * blockDim.x + threadIdx.x;
    if (i < NNODES) dinv[i] = rsqrtf(1.0f + (float)cnt[i]);
}

// ---- hierarchical scan: 196-block partials -> 1-block scan -> local scan ----
__global__ __launch_bounds__(256) void k_scan_part(const int* cnt, int* part) {
    __shared__ int s[256];
    int i = blockIdx.x * 256 + threadIdx.x;
    s[threadIdx.x] = (i < NNODES) ? cnt[i] : 0;
    __syncthreads();
    for (int off = 128; off > 0; off >>= 1) {
        if (threadIdx.x < off) s[threadIdx.x] += s[threadIdx.x + off];
        __syncthreads();
    }
    if (threadIdx.x == 0) part[blockIdx.x] = s[0];
}

__global__ __launch_bounds__(256) void k_scan_off(int* part, int n) {
    __shared__ int s[256];
    int v = (threadIdx.x < n) ? part[threadIdx.x] : 0;
    s[threadIdx.x] = v;
    __syncthreads();
    for (int off = 1; off < 256; off <<= 1) {
        int t = (threadIdx.x >= off) ? s[threadIdx.x - off] : 0;
        __syncthreads();
        s[threadIdx.x] += t;
        __syncthreads();
    }
    if (threadIdx.x < n) part[threadIdx.x] = s[threadIdx.x] - v;  // exclusive
}

__global__ __launch_bounds__(256) void k_scan_fin(const int* cnt, const int* part,
                                                  int* rowptr, int* cursor) {
    __shared__ int s[256];
    int i = blockIdx.x * 256 + threadIdx.x;
    int v = (i < NNODES) ? cnt[i] : 0;
    s[threadIdx.x] = v;
    __syncthreads();
    for (int off = 1; off < 256; off <<= 1) {
        int t = (threadIdx.x >= off) ? s[threadIdx.x - off] : 0;
        __syncthreads();
        s[threadIdx.x] += t;
        __syncthreads();
    }
    int incl = s[threadIdx.x] + part[blockIdx.x];
    if (i < NNODES) {
        rowptr[i + 1] = incl;
        cursor[i] = incl - v;
    }
    if (i == 0) rowptr[0] = 0;
}

__global__ void k_fill(const void* ei, int* cursor, int* csr_src, const int* flags) {
    int e = blockIdx.x * blockDim.x + threadIdx.x;
    if (e >= NEDGES) return;
    int is64 = flags[1];
    int v = eidx(ei, 1, e, is64);
    int u = eidx(ei, 0, e, is64);
    int pos = atomicAdd(&cursor[v], 1);
    csr_src[pos] = u;
}

// ---------------- GEMM1 MFMA: h1c[:, 0:C] = x @ W1[:, c0:c0+C] ----------------
__global__ __launch_bounds__(256) void k_gemm1_mfma(
    const void* __restrict__ X, const bf16* __restrict__ W1T,
    bf16* __restrict__ h1c, int c0, int C, const int* __restrict__ flags) {
    __shared__ bf16 As[128 * 64];
    __shared__ bf16 Bs[64 * 64];
    const int tid = threadIdx.x;
    const int wave = tid >> 6, lane = tid & 63;
    const int row0 = blockIdx.x * 128;
    const int gc0 = c0 + blockIdx.y * 64;
    const int isb = flags[0];

    float4v acc[2][4];
#pragma unroll
    for (int i = 0; i < 2; i++)
#pragma unroll
        for (int j = 0; j < 4; j++) acc[i][j] = (float4v){0.f, 0.f, 0.f, 0.f};

    const int rbase = wave * 32;
    const int fl_row = lane & 15;
    const int fl_k8 = (lane >> 4) * 8;

    for (int k0 = 0; k0 < DFEAT; k0 += 64) {
        __syncthreads();
        if (isb) {
            const bf16* xb = (const bf16*)X;
#pragma unroll
            for (int i = 0; i < 4; ++i) {
                int r = i * 32 + wave * 8;
                int gr = row0 + r + (lane >> 3);
                if (gr >= NNODES) gr = NNODES - 1;
                load_lds16(xb + (size_t)gr * DFEAT + k0 + (lane & 7) * 8, &As[r * 64]);
            }
        } else {
            const float* xf = (const float*)X;
            for (int i = tid; i < 128 * 64; i += 256) {
                int r = i >> 6, c = i & 63;
                int gr = row0 + r;
                if (gr >= NNODES) gr = NNODES - 1;
                As[i] = __float2bfloat16(xf[(size_t)gr * DFEAT + k0 + c]);
            }
        }
#pragma unroll
        for (int i = 0; i < 2; ++i) {
            int r = i * 32 + wave * 8;
            int gn = gc0 + r + (lane >> 3);
            load_lds16(W1T + (size_t)gn * DFEAT + k0 + (lane & 7) * 8, &Bs[r * 64]);
        }
        __syncthreads();
#pragma unroll
        for (int ki = 0; ki < 64; ki += 32) {
            short8 a[2], b[4];
#pragma unroll
            for (int i = 0; i < 2; i++)
                a[i] = *(const short8*)&As[(rbase + i * 16 + fl_row) * 64 + ki + fl_k8];
#pragma unroll
            for (int j = 0; j < 4; j++)
                b[j] = *(const short8*)&Bs[(j * 16 + fl_row) * 64 + ki + fl_k8];
#pragma unroll
            for (int i = 0; i < 2; i++)
#pragma unroll
                for (int j = 0; j < 4; j++)
                    acc[i][j] = __builtin_amdgcn_mfma_f32_16x16x32_bf16(a[i], b[j], acc[i][j], 0, 0, 0);
        }
    }
    const int ccol = blockIdx.y * 64;
#pragma unroll
    for (int i = 0; i < 2; i++) {
#pragma unroll
        for (int r = 0; r < 4; r++) {
            int grow = row0 + rbase + i * 16 + (lane >> 4) * 4 + r;
            if (grow < NNODES) {
#pragma unroll
                for (int j = 0; j < 4; j++)
                    h1c[(size_t)grow * C + ccol + j * 16 + (lane & 15)] =
                        __float2bfloat16(acc[i][j][r]);
            }
        }
    }
}

// ---------------- layer1 aggregation (CSR gather, 4 bf16/thread) ----------------
__global__ __launch_bounds__(256) void k_agg1(const bf16* __restrict__ h1c,
                                              const int* __restrict__ rowptr,
                                              const int* __restrict__ csr_src,
                                              const float* __restrict__ dinv,
                                              const float* __restrict__ b1c, int c0, int C,
                                              bf16* __restrict__ a1c) {
    const int tshift = (C == 256) ? 6 : (C == 128) ? 5 : 4;  // threads per node = C/4
    long long gt = (long long)blockIdx.x * 256 + threadIdx.x;
    int v = (int)(gt >> tshift);
    int d4 = (int)((gt & ((1 << tshift) - 1)) << 2);
    if (v >= NNODES) return;
    float dv = dinv[v];
    uint2 w = *(const uint2*)(h1c + (size_t)v * C + d4);
    float s2 = dv * dv;
    float a0 = s2 * bfbits_lo(w.x), a1 = s2 * bfbits_hi(w.x);
    float a2 = s2 * bfbits_lo(w.y), a3 = s2 * bfbits_hi(w.y);
    int pend = rowptr[v + 1];
    for (int p = rowptr[v]; p < pend; ++p) {
        int u = csr_src[p];
        float nw = dinv[u] * dv;
        uint2 q = *(const uint2*)(h1c + (size_t)u * C + d4);
        a0 += nw * bfbits_lo(q.x); a1 += nw * bfbits_hi(q.x);
        a2 += nw * bfbits_lo(q.y); a3 += nw * bfbits_hi(q.y);
    }
    const float* bb = b1c + c0 + d4;
    a0 += bb[0]; a1 += bb[1]; a2 += bb[2]; a3 += bb[3];
    bf16 o[4];
    o[0] = __float2bfloat16(a0 > 0.f ? a0 : 0.f);
    o[1] = __float2bfloat16(a1 > 0.f ? a1 : 0.f);
    o[2] = __float2bfloat16(a2 > 0.f ? a2 : 0.f);
    o[3] = __float2bfloat16(a3 > 0.f ? a3 : 0.f);
    *(uint2*)(a1c + (size_t)v * C + d4) = *(uint2*)o;
}

// ---------------- GEMM2 MFMA: h2[:, 0:47] (+)= a1c @ W2T^T ----------------
__global__ __launch_bounds__(256) void k_gemm2_mfma(
    const bf16* __restrict__ A, int C, const bf16* __restrict__ W2T, int kg0,
    float* __restrict__ h2, int accum) {
    __shared__ bf16 As[128 * 64];
    __shared__ bf16 Bs[64 * 64];
    const int tid = threadIdx.x;
    const int wave = tid >> 6, lane = tid & 63;
    const int row0 = blockIdx.x * 128;

    float4v acc[2][4];
#pragma unroll
    for (int i = 0; i < 2; i++)
#pragma unroll
        for (int j = 0; j < 4; j++) acc[i][j] = (float4v){0.f, 0.f, 0.f, 0.f};

    const int rbase = wave * 32;
    const int fl_row = lane & 15;
    const int fl_k8 = (lane >> 4) * 8;

    for (int kk = 0; kk < C; kk += 64) {
        __syncthreads();
#pragma unroll
        for (int i = 0; i < 4; ++i) {
            int r = i * 32 + wave * 8;
            int gr = row0 + r + (lane >> 3);
            if (gr >= NNODES) gr = NNODES - 1;
            load_lds16(A + (size_t)gr * C + kk + (lane & 7) * 8, &As[r * 64]);
        }
#pragma unroll
        for (int i = 0; i < 2; ++i) {
            int r = i * 32 + wave * 8;
            int gn = r + (lane >> 3);
            load_lds16(W2T + (size_t)gn * HID + kg0 + kk + (lane & 7) * 8, &Bs[r * 64]);
        }
        __syncthreads();
#pragma unroll
        for (int ki = 0; ki < 64; ki += 32) {
            short8 a[2], b[4];
#pragma unroll
            for (int i = 0; i < 2; i++)
                a[i] = *(const short8*)&As[(rbase + i * 16 + fl_row) * 64 + ki + fl_k8];
#pragma unroll
            for (int j = 0; j < 4; j++)
                b[j] = *(const short8*)&Bs[(j * 16 + fl_row) * 64 + ki + fl_k8];
#pragma unroll
            for (int i = 0; i < 2; i++)
#pragma unroll
                for (int j = 0; j < 4; j++)
                    acc[i][j] = __builtin_amdgcn_mfma_f32_16x16x32_bf16(a[i], b[j], acc[i][j], 0, 0, 0);
        }
    }
#pragma unroll
    for (int i = 0; i < 2; i++) {
#pragma unroll
        for (int r = 0; r < 4; r++) {
            int grow = row0 + rbase + i * 16 + (lane >> 4) * 4 + r;
            if (grow < NNODES) {
#pragma unroll
                for (int j = 0; j < 4; j++) {
                    int col = j * 16 + (lane & 15);
                    if (col < NCLS) {
                        size_t o = (size_t)grow * NCLS + col;
                        h2[o] = accum ? h2[o] + acc[i][j][r] : acc[i][j][r];
                    }
                }
            }
        }
    }
}

// ---------------- layer2 aggregation + bias -> out ----------------
__global__ __launch_bounds__(256) void k_agg2(const float* __restrict__ h2,
                                              const int* __restrict__ rowptr,
                                              const int* __restrict__ csr_src,
                                              const float* __restrict__ dinv,
                                              const float* __restrict__ b2c,
                                              void* out, const int* flags) {
    int v = blockIdx.x * 4 + (threadIdx.x >> 6);
    int d = threadIdx.x & 63;
    if (v >= NNODES || d >= NCLS) return;
    float dv = dinv[v];
    float acc = dv * dv * h2[(size_t)v * NCLS + d];
    int pend = rowptr[v + 1];
    for (int p = rowptr[v]; p < pend; ++p) {
        int u = csr_src[p];
        acc += dinv[u] * dv * h2[(size_t)u * NCLS + d];
    }
    acc += b2c[d];
    size_t o = (size_t)v * NCLS + d;
    if (flags[0]) ((bf16*)out)[o] = __float2bfloat16(acc);
    else          ((float*)out)[o] = acc;
}

extern "C" void kernel_launch(void* const* d_in, const int* in_sizes, int n_in,
                              void* d_out, int out_size, void* d_ws, size_t ws_size,
                              hipStream_t stream) {
    const void* x  = d_in[0];
    const void* ei = d_in[1];
    const void* W1 = d_in[2];
    const void* b1 = d_in[3];
    const void* W2 = d_in[4];
    const void* b2 = d_in[5];

    char* base = (char*)d_ws;
    auto alloc = [&](size_t bytes) -> char* {
        char* p = base;
        base += (bytes + 255) & ~(size_t)255;
        return p;
    };
    int*   flags  = (int*)alloc(64);
    int*   cnt    = (int*)alloc(sizeof(int) * NNODES);
    int*   part   = (int*)alloc(sizeof(int) * 256);
    int*   rowptr = (int*)alloc(sizeof(int) * (NNODES + 1));
    int*   cursor = (int*)alloc(sizeof(int) * NNODES);
    int*   csr    = (int*)alloc(sizeof(int) * NEDGES);
    float* dinv   = (float*)alloc(sizeof(float) * NNODES);
    bf16*  W1T    = (bf16*)alloc(sizeof(bf16) * DFEAT * HID);
    float* b1c    = (float*)alloc(sizeof(float) * HID);
    bf16*  W2T    = (bf16*)alloc(sizeof(bf16) * 64 * HID);
    float* b2c    = (float*)alloc(sizeof(float) * 64);
    float* h2     = (float*)alloc(sizeof(float) * (size_t)NNODES * NCLS);

    size_t used = (size_t)(base - (char*)d_ws);
    size_t rem = (ws_size > used) ? ws_size - used : 0;
    int C = 64;
    if (rem >= (size_t)200000 * 256 + 1024) C = 256;
    else if (rem >= (size_t)200000 * 128 + 1024) C = 128;
    bf16* h1c = (bf16*)alloc(sizeof(bf16) * (size_t)NNODES * C);
    bf16* a1c = (bf16*)alloc(sizeof(bf16) * (size_t)NNODES * C);

    k_detect<<<1, 64, 0, stream>>>(x, ei, flags);
    k_zero32<<<(NNODES + 255) / 256, 256, 0, stream>>>((unsigned int*)cnt, NNODES);

    k_cvt_w1t<<<(DFEAT * HID + 255) / 256, 256, 0, stream>>>(W1, W1T, flags);
    k_cvt<<<(HID + 255) / 256, 256, 0, stream>>>(b1, b1c, HID, flags);
    k_cvt_w2t<<<(64 * HID + 255) / 256, 256, 0, stream>>>(W2, W2T, flags);
    k_cvt<<<1, 64, 0, stream>>>(b2, b2c, NCLS, flags);

    k_count<<<(NEDGES + 255) / 256, 256, 0, stream>>>(ei, cnt, flags);
    k_dinv<<<(NNODES + 255) / 256, 256, 0, stream>>>(cnt, dinv);
    const int nsb = (NNODES + 255) / 256;  // 196
    k_scan_part<<<nsb, 256, 0, stream>>>(cnt, part);
    k_scan_off<<<1, 256, 0, stream>>>(part, nsb);
    k_scan_fin<<<nsb, 256, 0, stream>>>(cnt, part, rowptr, cursor);
    k_fill<<<(NEDGES + 255) / 256, 256, 0, stream>>>(ei, cursor, csr, flags);

    const int rowblocks = (NNODES + 127) / 128;  // 391
    int chunk_i = 0;
    for (int c0 = 0; c0 < HID; c0 += C, ++chunk_i) {
        dim3 g1(rowblocks, C / 64);
        k_gemm1_mfma<<<g1, 256, 0, stream>>>(x, W1T, h1c, c0, C, flags);
        size_t nthr = (size_t)NNODES * (C / 4);
        k_agg1<<<(int)((nthr + 255) / 256), 256, 0, stream>>>(h1c, rowptr, csr, dinv, b1c, c0, C, a1c);
        k_gemm2_mfma<<<rowblocks, 256, 0, stream>>>(a1c, C, W2T, c0, h2, chunk_i > 0 ? 1 : 0);
    }

    k_agg2<<<(NNODES + 3) / 4, 256, 0, stream>>>(h2, rowptr, csr, dinv, b2c, d_out, flags);
}

// Round 5
// 362.027 us; speedup vs baseline: 4.4888x; 1.2115x over previous
//
#include <hip/hip_runtime.h>
#include <hip/hip_bf16.h>

#define NNODES 50000
#define NEDGES 150000
#define DFEAT  512
#define HID    512
#define NCLS   47

typedef __hip_bfloat16 bf16;
typedef __attribute__((ext_vector_type(8))) short short8;
typedef __attribute__((ext_vector_type(4))) float float4v;

typedef const __attribute__((address_space(1))) unsigned int* gas_t;
typedef __attribute__((address_space(3))) unsigned int* las_t;
__device__ __forceinline__ void load_lds16(const void* g, void* l) {
    __builtin_amdgcn_global_load_lds((gas_t)g, (las_t)l, 16, 0, 0);
}

__device__ __forceinline__ float bfbits_lo(unsigned int w) {
    return __uint_as_float((w & 0xFFFFu) << 16);
}
__device__ __forceinline__ float bfbits_hi(unsigned int w) {
    return __uint_as_float(w & 0xFFFF0000u);
}

// ---------------- dtype detection (1 block, 64 threads) ----------------
__global__ void k_detect(const void* x, const void* ei, int* flags) {
    __shared__ int scnt[64], sor[64];
    int t = threadIdx.x;
    const unsigned short* xs = (const unsigned short*)x;
    int c = 0;
    for (int i = t; i < 256; i += 64) {
        unsigned int e = (xs[2 * i] >> 7) & 0xFF;
        c += (e >= 117 && e <= 130) ? 1 : 0;
    }
    const int* w = (const int*)ei;
    int o = 0;
    for (int i = 2 * t + 1; i < 512; i += 128) o |= w[i];
    scnt[t] = c; sor[t] = o;
    __syncthreads();
    if (t == 0) {
        int C = 0, O = 0;
        for (int i = 0; i < 64; i++) { C += scnt[i]; O |= sor[i]; }
        flags[0] = (C > 128) ? 1 : 0;
        flags[1] = (O == 0) ? 1 : 0;
    }
}

__device__ __forceinline__ int eidx(const void* ei, int half, int e, int is64) {
    if (is64) return (int)((const long long*)ei)[(size_t)half * NEDGES + e];
    return ((const int*)ei)[half * NEDGES + e];
}

// ---------------- utility ----------------
__global__ void k_zero32(unsigned int* p, size_t n) {
    size_t i = (size_t)blockIdx.x * blockDim.x + threadIdx.x;
    if (i < n) p[i] = 0u;
}

__global__ void k_cvt(const void* src, float* dst, int n, const int* flags) {
    int i = blockIdx.x * blockDim.x + threadIdx.x;
    if (i >= n) return;
    dst[i] = flags[0] ? __bfloat162float(((const bf16*)src)[i]) : ((const float*)src)[i];
}

// W1 [K=512][N=512] -> W1T bf16 [N][K]
__global__ void k_cvt_w1t(const void* W1, bf16* W1T, const int* flags) {
    int i = blockIdx.x * blockDim.x + threadIdx.x;
    if (i >= DFEAT * HID) return;
    int k = i / HID, n = i % HID;
    float v = flags[0] ? __bfloat162float(((const bf16*)W1)[i]) : ((const float*)W1)[i];
    W1T[(size_t)n * DFEAT + k] = __float2bfloat16(v);
}

// W2 [K=512][N=47] -> W2T bf16 [64][512] zero-padded
__global__ void k_cvt_w2t(const void* W2, bf16* W2T, const int* flags) {
    int i = blockIdx.x * blockDim.x + threadIdx.x;
    if (i >= 64 * HID) return;
    int n = i / HID, k = i % HID;
    float v = 0.0f;
    if (n < NCLS) {
        size_t idx = (size_t)k * NCLS + n;
        v = flags[0] ? __bfloat162float(((const bf16*)W2)[idx]) : ((const float*)W2)[idx];
    }
    W2T[(size_t)n * HID + k] = __float2bfloat16(v);
}

// ---------------- graph structure ----------------
__global__ void k_count(const void* ei, int* cnt, const int* flags) {
    int e = blockIdx.x * blockDim.x + threadIdx.x;
    if (e >= NEDGES) return;
    atomicAdd(&cnt[eidx(ei, 1, e, flags[1])], 1);
}

__global__ void k_dinv(const int* cnt, float* dinv) {
    int i = blockIdx.x * blockDim.x + threadIdx.x;
    if (i < NNODES) dinv[i] = rsqrtf(1.0f + (float)cnt[i]);
}

__global__ __launch_bounds__(256) void k_scan_part(const int* cnt, int* part) {
    __shared__ int s[256];
    int i = blockIdx.x * 256 + threadIdx.x;
    s[threadIdx.x] = (i < NNODES) ? cnt[i] : 0;
    __syncthreads();
    for (int off = 128; off > 0; off >>= 1) {
        if (threadIdx.x < off) s[threadIdx.x] += s[threadIdx.x + off];
        __syncthreads();
    }
    if (threadIdx.x == 0) part[blockIdx.x] = s[0];
}

__global__ __launch_bounds__(256) void k_scan_off(int* part, int n) {
    __shared__ int s[256];
    int v = (threadIdx.x < n) ? part[threadIdx.x] : 0;
    s[threadIdx.x] = v;
    __syncthreads();
    for (int off = 1; off < 256; off <<= 1) {
        int t = (threadIdx.x >= off) ? s[threadIdx.x - off] : 0;
        __syncthreads();
        s[threadIdx.x] += t;
        __syncthreads();
    }
    if (threadIdx.x < n) part[threadIdx.x] = s[threadIdx.x] - v;
}

__global__ __launch_bounds__(256) void k_scan_fin(const int* cnt, const int* part,
                                                  int* rowptr, int* cursor) {
    __shared__ int s[256];
    int i = blockIdx.x * 256 + threadIdx.x;
    int v = (i < NNODES) ? cnt[i] : 0;
    s[threadIdx.x] = v;
    __syncthreads();
    for (int off = 1; off < 256; off <<= 1) {
        int t = (threadIdx.x >= off) ? s[threadIdx.x - off] : 0;
        __syncthreads();
        s[threadIdx.x] += t;
        __syncthreads();
    }
    int incl = s[threadIdx.x] + part[blockIdx.x];
    if (i < NNODES) {
        rowptr[i + 1] = incl;
        cursor[i] = incl - v;
    }
    if (i == 0) rowptr[0] = 0;
}

__global__ void k_fill(const void* ei, int* cursor, int* csr_src, const int* flags) {
    int e = blockIdx.x * blockDim.x + threadIdx.x;
    if (e >= NEDGES) return;
    int is64 = flags[1];
    int v = eidx(ei, 1, e, is64);
    int u = eidx(ei, 0, e, is64);
    int pos = atomicAdd(&cursor[v], 1);
    csr_src[pos] = u;
}

// ---------------- GEMM1 v3: 128x128 block, XOR-swizzled LDS, col-tile-major grid ----
// As/Bs layout: tile[r][p] (p = chunk pos 0..7, 8 bf16/chunk) holds content chunk
// ck = p ^ (r&7)  ->  elements A[row0+r][k0 + ck*8 .. +8).
__global__ __launch_bounds__(256, 3) void k_gemm1_v3(
    const void* __restrict__ X, const bf16* __restrict__ W1T,
    bf16* __restrict__ h1c, int c0, int C, const int* __restrict__ flags) {
    __shared__ bf16 As[128 * 64];
    __shared__ bf16 Bs[128 * 64];
    const int tid = threadIdx.x;
    const int wave = tid >> 6, lane = tid & 63;
    const int row0 = blockIdx.y * 128;
    const int gc0 = c0 + blockIdx.x * 128;  // global col base
    const int isb = flags[0];

    float4v acc[2][8];
#pragma unroll
    for (int i = 0; i < 2; i++)
#pragma unroll
        for (int j = 0; j < 8; j++) acc[i][j] = (float4v){0.f, 0.f, 0.f, 0.f};

    const int rb = wave * 32;       // wave row base (wave tile 32x128)
    const int frow = lane & 15;
    const int fk = lane >> 4;       // 0..3

    for (int k0 = 0; k0 < DFEAT; k0 += 64) {
        __syncthreads();
        if (isb) {
            const bf16* xb = (const bf16*)X;
#pragma unroll
            for (int t = 0; t < 4; ++t) {
                int g8 = wave * 4 + t;                    // 8-row group 0..15
                int r = g8 * 8 + (lane >> 3);
                int gr = row0 + r; if (gr >= NNODES) gr = NNODES - 1;
                int ck = (lane & 7) ^ (r & 7);            // content chunk for dst pos lane&7
                load_lds16(xb + (size_t)gr * DFEAT + k0 + ck * 8, &As[g8 * 8 * 64]);
            }
        } else {
            const float* xf = (const float*)X;
            for (int i = tid; i < 128 * 8; i += 256) {    // i = r*8 + p
                int r = i >> 3, p = i & 7;
                int gr = row0 + r; if (gr >= NNODES) gr = NNODES - 1;
                int ck = p ^ (r & 7);
                const float* src = xf + (size_t)gr * DFEAT + k0 + ck * 8;
#pragma unroll
                for (int e = 0; e < 8; ++e)
                    As[r * 64 + p * 8 + e] = __float2bfloat16(src[e]);
            }
        }
#pragma unroll
        for (int t = 0; t < 4; ++t) {
            int g8 = wave * 4 + t;
            int cl = g8 * 8 + (lane >> 3);
            int ck = (lane & 7) ^ (cl & 7);
            load_lds16(W1T + (size_t)(gc0 + cl) * DFEAT + k0 + ck * 8, &Bs[g8 * 8 * 64]);
        }
        __syncthreads();
#pragma unroll
        for (int ki = 0; ki < 2; ++ki) {
            const int cc = ki * 4 + fk;                   // content chunk within tile
            short8 a[2], b[8];
#pragma unroll
            for (int i = 0; i < 2; i++) {
                int r = rb + i * 16 + frow;
                a[i] = *(const short8*)&As[r * 64 + (cc ^ (r & 7)) * 8];
            }
#pragma unroll
            for (int j = 0; j < 8; j++) {
                int cl = j * 16 + frow;
                b[j] = *(const short8*)&Bs[cl * 64 + (cc ^ (cl & 7)) * 8];
            }
#pragma unroll
            for (int i = 0; i < 2; i++)
#pragma unroll
                for (int j = 0; j < 8; j++)
                    acc[i][j] = __builtin_amdgcn_mfma_f32_16x16x32_bf16(a[i], b[j], acc[i][j], 0, 0, 0);
        }
    }
    const int ccol = gc0 - c0;  // col base within h1c chunk
#pragma unroll
    for (int i = 0; i < 2; i++) {
#pragma unroll
        for (int r = 0; r < 4; r++) {
            int grow = row0 + rb + i * 16 + (lane >> 4) * 4 + r;
            if (grow < NNODES) {
#pragma unroll
                for (int j = 0; j < 8; j++)
                    h1c[(size_t)grow * C + ccol + j * 16 + (lane & 15)] =
                        __float2bfloat16(acc[i][j][r]);
            }
        }
    }
}

// ---------------- legacy GEMM1 (used only for C==64 fallback) ----------------
__global__ __launch_bounds__(256) void k_gemm1_mfma(
    const void* __restrict__ X, const bf16* __restrict__ W1T,
    bf16* __restrict__ h1c, int c0, int C, const int* __restrict__ flags) {
    __shared__ bf16 As[128 * 64];
    __shared__ bf16 Bs[64 * 64];
    const int tid = threadIdx.x;
    const int wave = tid >> 6, lane = tid & 63;
    const int row0 = blockIdx.x * 128;
    const int gc0 = c0 + blockIdx.y * 64;
    const int isb = flags[0];
    float4v acc[2][4];
#pragma unroll
    for (int i = 0; i < 2; i++)
#pragma unroll
        for (int j = 0; j < 4; j++) acc[i][j] = (float4v){0.f, 0.f, 0.f, 0.f};
    const int rbase = wave * 32;
    const int fl_row = lane & 15;
    const int fl_k8 = (lane >> 4) * 8;
    for (int k0 = 0; k0 < DFEAT; k0 += 64) {
        __syncthreads();
        if (isb) {
            const bf16* xb = (const bf16*)X;
#pragma unroll
            for (int i = 0; i < 4; ++i) {
                int r = i * 32 + wave * 8;
                int gr = row0 + r + (lane >> 3);
                if (gr >= NNODES) gr = NNODES - 1;
                load_lds16(xb + (size_t)gr * DFEAT + k0 + (lane & 7) * 8, &As[r * 64]);
            }
        } else {
            const float* xf = (const float*)X;
            for (int i = tid; i < 128 * 64; i += 256) {
                int r = i >> 6, c = i & 63;
                int gr = row0 + r;
                if (gr >= NNODES) gr = NNODES - 1;
                As[i] = __float2bfloat16(xf[(size_t)gr * DFEAT + k0 + c]);
            }
        }
#pragma unroll
        for (int i = 0; i < 2; ++i) {
            int r = i * 32 + wave * 8;
            int gn = gc0 + r + (lane >> 3);
            load_lds16(W1T + (size_t)gn * DFEAT + k0 + (lane & 7) * 8, &Bs[r * 64]);
        }
        __syncthreads();
#pragma unroll
        for (int ki = 0; ki < 64; ki += 32) {
            short8 a[2], b[4];
#pragma unroll
            for (int i = 0; i < 2; i++)
                a[i] = *(const short8*)&As[(rbase + i * 16 + fl_row) * 64 + ki + fl_k8];
#pragma unroll
            for (int j = 0; j < 4; j++)
                b[j] = *(const short8*)&Bs[(j * 16 + fl_row) * 64 + ki + fl_k8];
#pragma unroll
            for (int i = 0; i < 2; i++)
#pragma unroll
                for (int j = 0; j < 4; j++)
                    acc[i][j] = __builtin_amdgcn_mfma_f32_16x16x32_bf16(a[i], b[j], acc[i][j], 0, 0, 0);
        }
    }
    const int ccol = blockIdx.y * 64;
#pragma unroll
    for (int i = 0; i < 2; i++) {
#pragma unroll
        for (int r = 0; r < 4; r++) {
            int grow = row0 + rbase + i * 16 + (lane >> 4) * 4 + r;
            if (grow < NNODES) {
#pragma unroll
                for (int j = 0; j < 4; j++)
                    h1c[(size_t)grow * C + ccol + j * 16 + (lane & 15)] =
                        __float2bfloat16(acc[i][j][r]);
            }
        }
    }
}

// ---------------- layer1 aggregation (CSR gather, 4 bf16/thread) ----------------
__global__ __launch_bounds__(256) void k_agg1(const bf16* __restrict__ h1c,
                                              const int* __restrict__ rowptr,
                                              const int* __restrict__ csr_src,
                                              const float* __restrict__ dinv,
                                              const float* __restrict__ b1c, int c0, int C,
                                              bf16* __restrict__ a1c) {
    const int tshift = (C == 512) ? 7 : (C == 256) ? 6 : (C == 128) ? 5 : 4;
    long long gt = (long long)blockIdx.x * 256 + threadIdx.x;
    int v = (int)(gt >> tshift);
    int d4 = (int)((gt & ((1 << tshift) - 1)) << 2);
    if (v >= NNODES) return;
    float dv = dinv[v];
    uint2 w = *(const uint2*)(h1c + (size_t)v * C + d4);
    float s2 = dv * dv;
    float a0 = s2 * bfbits_lo(w.x), a1 = s2 * bfbits_hi(w.x);
    float a2 = s2 * bfbits_lo(w.y), a3 = s2 * bfbits_hi(w.y);
    int pend = rowptr[v + 1];
    for (int p = rowptr[v]; p < pend; ++p) {
        int u = csr_src[p];
        float nw = dinv[u] * dv;
        uint2 q = *(const uint2*)(h1c + (size_t)u * C + d4);
        a0 += nw * bfbits_lo(q.x); a1 += nw * bfbits_hi(q.x);
        a2 += nw * bfbits_lo(q.y); a3 += nw * bfbits_hi(q.y);
    }
    const float* bb = b1c + c0 + d4;
    a0 += bb[0]; a1 += bb[1]; a2 += bb[2]; a3 += bb[3];
    bf16 o[4];
    o[0] = __float2bfloat16(a0 > 0.f ? a0 : 0.f);
    o[1] = __float2bfloat16(a1 > 0.f ? a1 : 0.f);
    o[2] = __float2bfloat16(a2 > 0.f ? a2 : 0.f);
    o[3] = __float2bfloat16(a3 > 0.f ? a3 : 0.f);
    *(uint2*)(a1c + (size_t)v * C + d4) = *(uint2*)o;
}

// ---------------- GEMM2 MFMA: h2[:, 0:47] (+)= a1c @ W2T^T ----------------
__global__ __launch_bounds__(256) void k_gemm2_mfma(
    const bf16* __restrict__ A, int C, const bf16* __restrict__ W2T, int kg0,
    float* __restrict__ h2, int accum) {
    __shared__ bf16 As[128 * 64];
    __shared__ bf16 Bs[64 * 64];
    const int tid = threadIdx.x;
    const int wave = tid >> 6, lane = tid & 63;
    const int row0 = blockIdx.x * 128;
    float4v acc[2][4];
#pragma unroll
    for (int i = 0; i < 2; i++)
#pragma unroll
        for (int j = 0; j < 4; j++) acc[i][j] = (float4v){0.f, 0.f, 0.f, 0.f};
    const int rbase = wave * 32;
    const int fl_row = lane & 15;
    const int fl_k8 = (lane >> 4) * 8;
    for (int kk = 0; kk < C; kk += 64) {
        __syncthreads();
#pragma unroll
        for (int i = 0; i < 4; ++i) {
            int r = i * 32 + wave * 8;
            int gr = row0 + r + (lane >> 3);
            if (gr >= NNODES) gr = NNODES - 1;
            load_lds16(A + (size_t)gr * C + kk + (lane & 7) * 8, &As[r * 64]);
        }
#pragma unroll
        for (int i = 0; i < 2; ++i) {
            int r = i * 32 + wave * 8;
            int gn = r + (lane >> 3);
            load_lds16(W2T + (size_t)gn * HID + kg0 + kk + (lane & 7) * 8, &Bs[r * 64]);
        }
        __syncthreads();
#pragma unroll
        for (int ki = 0; ki < 64; ki += 32) {
            short8 a[2], b[4];
#pragma unroll
            for (int i = 0; i < 2; i++)
                a[i] = *(const short8*)&As[(rbase + i * 16 + fl_row) * 64 + ki + fl_k8];
#pragma unroll
            for (int j = 0; j < 4; j++)
                b[j] = *(const short8*)&Bs[(j * 16 + fl_row) * 64 + ki + fl_k8];
#pragma unroll
            for (int i = 0; i < 2; i++)
#pragma unroll
                for (int j = 0; j < 4; j++)
                    acc[i][j] = __builtin_amdgcn_mfma_f32_16x16x32_bf16(a[i], b[j], acc[i][j], 0, 0, 0);
        }
    }
#pragma unroll
    for (int i = 0; i < 2; i++) {
#pragma unroll
        for (int r = 0; r < 4; r++) {
            int grow = row0 + rbase + i * 16 + (lane >> 4) * 4 + r;
            if (grow < NNODES) {
#pragma unroll
                for (int j = 0; j < 4; j++) {
                    int col = j * 16 + (lane & 15);
                    if (col < NCLS) {
                        size_t o = (size_t)grow * NCLS + col;
                        h2[o] = accum ? h2[o] + acc[i][j][r] : acc[i][j][r];
                    }
                }
            }
        }
    }
}

// ---------------- layer2 aggregation + bias -> out ----------------
__global__ __launch_bounds__(256) void k_agg2(const float* __restrict__ h2,
                                              const int* __restrict__ rowptr,
                                              const int* __restrict__ csr_src,
                                              const float* __restrict__ dinv,
                                              const float* __restrict__ b2c,
                                              void* out, const int* flags) {
    int v = blockIdx.x * 4 + (threadIdx.x >> 6);
    int d = threadIdx.x & 63;
    if (v >= NNODES || d >= NCLS) return;
    float dv = dinv[v];
    float acc = dv * dv * h2[(size_t)v * NCLS + d];
    int pend = rowptr[v + 1];
    for (int p = rowptr[v]; p < pend; ++p) {
        int u = csr_src[p];
        acc += dinv[u] * dv * h2[(size_t)u * NCLS + d];
    }
    acc += b2c[d];
    size_t o = (size_t)v * NCLS + d;
    if (flags[0]) ((bf16*)out)[o] = __float2bfloat16(acc);
    else          ((float*)out)[o] = acc;
}

extern "C" void kernel_launch(void* const* d_in, const int* in_sizes, int n_in,
                              void* d_out, int out_size, void* d_ws, size_t ws_size,
                              hipStream_t stream) {
    const void* x  = d_in[0];
    const void* ei = d_in[1];
    const void* W1 = d_in[2];
    const void* b1 = d_in[3];
    const void* W2 = d_in[4];
    const void* b2 = d_in[5];

    char* base = (char*)d_ws;
    auto alloc = [&](size_t bytes) -> char* {
        char* p = base;
        base += (bytes + 255) & ~(size_t)255;
        return p;
    };
    int*   flags  = (int*)alloc(64);
    int*   cnt    = (int*)alloc(sizeof(int) * NNODES);
    int*   part   = (int*)alloc(sizeof(int) * 256);
    int*   rowptr = (int*)alloc(sizeof(int) * (NNODES + 1));
    int*   cursor = (int*)alloc(sizeof(int) * NNODES);
    int*   csr    = (int*)alloc(sizeof(int) * NEDGES);
    float* dinv   = (float*)alloc(sizeof(float) * NNODES);
    bf16*  W1T    = (bf16*)alloc(sizeof(bf16) * DFEAT * HID);
    float* b1c    = (float*)alloc(sizeof(float) * HID);
    bf16*  W2T    = (bf16*)alloc(sizeof(bf16) * 64 * HID);
    float* b2c    = (float*)alloc(sizeof(float) * 64);
    float* h2     = (float*)alloc(sizeof(float) * (size_t)NNODES * NCLS);

    size_t used = (size_t)(base - (char*)d_ws);
    size_t rem = (ws_size > used) ? ws_size - used : 0;
    int C = 64;
    if (rem >= (size_t)200000 * 512 + 1024) C = 512;
    else if (rem >= (size_t)200000 * 256 + 1024) C = 256;
    else if (rem >= (size_t)200000 * 128 + 1024) C = 128;
    bf16* h1c = (bf16*)alloc(sizeof(bf16) * (size_t)NNODES * C);
    bf16* a1c = (bf16*)alloc(sizeof(bf16) * (size_t)NNODES * C);

    k_detect<<<1, 64, 0, stream>>>(x, ei, flags);
    k_zero32<<<(NNODES + 255) / 256, 256, 0, stream>>>((unsigned int*)cnt, NNODES);

    k_cvt_w1t<<<(DFEAT * HID + 255) / 256, 256, 0, stream>>>(W1, W1T, flags);
    k_cvt<<<(HID + 255) / 256, 256, 0, stream>>>(b1, b1c, HID, flags);
    k_cvt_w2t<<<(64 * HID + 255) / 256, 256, 0, stream>>>(W2, W2T, flags);
    k_cvt<<<1, 64, 0, stream>>>(b2, b2c, NCLS, flags);

    k_count<<<(NEDGES + 255) / 256, 256, 0, stream>>>(ei, cnt, flags);
    k_dinv<<<(NNODES + 255) / 256, 256, 0, stream>>>(cnt, dinv);
    const int nsb = (NNODES + 255) / 256;  // 196
    k_scan_part<<<nsb, 256, 0, stream>>>(cnt, part);
    k_scan_off<<<1, 256, 0, stream>>>(part, nsb);
    k_scan_fin<<<nsb, 256, 0, stream>>>(cnt, part, rowptr, cursor);
    k_fill<<<(NEDGES + 255) / 256, 256, 0, stream>>>(ei, cursor, csr, flags);

    const int rowblocks = (NNODES + 127) / 128;  // 391
    int chunk_i = 0;
    for (int c0 = 0; c0 < HID; c0 += C, ++chunk_i) {
        if (C >= 128) {
            // col-tile is blockIdx.x (fastest-varying) for L2/L3 row reuse
            dim3 g1(C / 128, rowblocks);
            k_gemm1_v3<<<g1, 256, 0, stream>>>(x, W1T, h1c, c0, C, flags);
        } else {
            dim3 g1(rowblocks, 1);
            k_gemm1_mfma<<<g1, 256, 0, stream>>>(x, W1T, h1c, c0, C, flags);
        }
        size_t nthr = (size_t)NNODES * (C / 4);
        k_agg1<<<(int)((nthr + 255) / 256), 256, 0, stream>>>(h1c, rowptr, csr, dinv, b1c, c0, C, a1c);
        k_gemm2_mfma<<<rowblocks, 256, 0, stream>>>(a1c, C, W2T, c0, h2, chunk_i > 0 ? 1 : 0);
    }

    k_agg2<<<(NNODES + 3) / 4, 256, 0, stream>>>(h2, rowptr, csr, dinv, b2c, d_out, flags);
}

// Round 6
// 349.219 us; speedup vs baseline: 4.6535x; 1.0367x over previous
//
#include <hip/hip_runtime.h>
#include <hip/hip_bf16.h>

#define NNODES 50000
#define NEDGES 150000
#define DFEAT  512
#define HID    512
#define NCLS   47

typedef __hip_bfloat16 bf16;
typedef __attribute__((ext_vector_type(8))) short short8;
typedef __attribute__((ext_vector_type(4))) float float4v;

typedef const __attribute__((address_space(1))) unsigned int* gas_t;
typedef __attribute__((address_space(3))) unsigned int* las_t;
__device__ __forceinline__ void load_lds16(const void* g, void* l) {
    __builtin_amdgcn_global_load_lds((gas_t)g, (las_t)l, 16, 0, 0);
}

__device__ __forceinline__ float bfbits_lo(unsigned int w) {
    return __uint_as_float((w & 0xFFFFu) << 16);
}
__device__ __forceinline__ float bfbits_hi(unsigned int w) {
    return __uint_as_float(w & 0xFFFF0000u);
}

// ---------------- dtype detection (1 block, 64 threads) ----------------
__global__ void k_detect(const void* x, const void* ei, int* flags) {
    __shared__ int scnt[64], sor[64];
    int t = threadIdx.x;
    const unsigned short* xs = (const unsigned short*)x;
    int c = 0;
    for (int i = t; i < 256; i += 64) {
        unsigned int e = (xs[2 * i] >> 7) & 0xFF;
        c += (e >= 117 && e <= 130) ? 1 : 0;
    }
    const int* w = (const int*)ei;
    int o = 0;
    for (int i = 2 * t + 1; i < 512; i += 128) o |= w[i];
    scnt[t] = c; sor[t] = o;
    __syncthreads();
    if (t == 0) {
        int C = 0, O = 0;
        for (int i = 0; i < 64; i++) { C += scnt[i]; O |= sor[i]; }
        flags[0] = (C > 128) ? 1 : 0;
        flags[1] = (O == 0) ? 1 : 0;
    }
}

__device__ __forceinline__ int eidx(const void* ei, int half, int e, int is64) {
    if (is64) return (int)((const long long*)ei)[(size_t)half * NEDGES + e];
    return ((const int*)ei)[half * NEDGES + e];
}

// ---------------- utility ----------------
__global__ void k_zero32(unsigned int* p, size_t n) {
    size_t i = (size_t)blockIdx.x * blockDim.x + threadIdx.x;
    if (i < n) p[i] = 0u;
}

__global__ void k_cvt(const void* src, float* dst, int n, const int* flags) {
    int i = blockIdx.x * blockDim.x + threadIdx.x;
    if (i >= n) return;
    dst[i] = flags[0] ? __bfloat162float(((const bf16*)src)[i]) : ((const float*)src)[i];
}

// W1 [K=512][N=512] -> W1T bf16 [N][K]
__global__ void k_cvt_w1t(const void* W1, bf16* W1T, const int* flags) {
    int i = blockIdx.x * blockDim.x + threadIdx.x;
    if (i >= DFEAT * HID) return;
    int k = i / HID, n = i % HID;
    float v = flags[0] ? __bfloat162float(((const bf16*)W1)[i]) : ((const float*)W1)[i];
    W1T[(size_t)n * DFEAT + k] = __float2bfloat16(v);
}

// W2 [K=512][N=47] -> W2T bf16 [64][512] zero-padded
__global__ void k_cvt_w2t(const void* W2, bf16* W2T, const int* flags) {
    int i = blockIdx.x * blockDim.x + threadIdx.x;
    if (i >= 64 * HID) return;
    int n = i / HID, k = i % HID;
    float v = 0.0f;
    if (n < NCLS) {
        size_t idx = (size_t)k * NCLS + n;
        v = flags[0] ? __bfloat162float(((const bf16*)W2)[idx]) : ((const float*)W2)[idx];
    }
    W2T[(size_t)n * HID + k] = __float2bfloat16(v);
}

// ---------------- graph structure ----------------
__global__ void k_count(const void* ei, int* cnt, const int* flags) {
    int e = blockIdx.x * blockDim.x + threadIdx.x;
    if (e >= NEDGES) return;
    atomicAdd(&cnt[eidx(ei, 1, e, flags[1])], 1);
}

__global__ void k_dinv(const int* cnt, float* dinv) {
    int i = blockIdx.x * blockDim.x + threadIdx.x;
    if (i < NNODES) dinv[i] = rsqrtf(1.0f + (float)cnt[i]);
}

__global__ __launch_bounds__(256) void k_scan_part(const int* cnt, int* part) {
    __shared__ int s[256];
    int i = blockIdx.x * 256 + threadIdx.x;
    s[threadIdx.x] = (i < NNODES) ? cnt[i] : 0;
    __syncthreads();
    for (int off = 128; off > 0; off >>= 1) {
        if (threadIdx.x < off) s[threadIdx.x] += s[threadIdx.x + off];
        __syncthreads();
    }
    if (threadIdx.x == 0) part[blockIdx.x] = s[0];
}

__global__ __launch_bounds__(256) void k_scan_off(int* part, int n) {
    __shared__ int s[256];
    int v = (threadIdx.x < n) ? part[threadIdx.x] : 0;
    s[threadIdx.x] = v;
    __syncthreads();
    for (int off = 1; off < 256; off <<= 1) {
        int t = (threadIdx.x >= off) ? s[threadIdx.x - off] : 0;
        __syncthreads();
        s[threadIdx.x] += t;
        __syncthreads();
    }
    if (threadIdx.x < n) part[threadIdx.x] = s[threadIdx.x] - v;
}

__global__ __launch_bounds__(256) void k_scan_fin(const int* cnt, const int* part,
                                                  int* rowptr, int* cursor) {
    __shared__ int s[256];
    int i = blockIdx.x * 256 + threadIdx.x;
    int v = (i < NNODES) ? cnt[i] : 0;
    s[threadIdx.x] = v;
    __syncthreads();
    for (int off = 1; off < 256; off <<= 1) {
        int t = (threadIdx.x >= off) ? s[threadIdx.x - off] : 0;
        __syncthreads();
        s[threadIdx.x] += t;
        __syncthreads();
    }
    int incl = s[threadIdx.x] + part[blockIdx.x];
    if (i < NNODES) {
        rowptr[i + 1] = incl;
        cursor[i] = incl - v;
    }
    if (i == 0) rowptr[0] = 0;
}

__global__ void k_fill(const void* ei, int* cursor, int* csr_src, const int* flags) {
    int e = blockIdx.x * blockDim.x + threadIdx.x;
    if (e >= NEDGES) return;
    int is64 = flags[1];
    int v = eidx(ei, 1, e, is64);
    int u = eidx(ei, 0, e, is64);
    int pos = atomicAdd(&cursor[v], 1);
    csr_src[pos] = u;
}

// ---------------- GEMM1 v3: 128x128, XOR-swizzled LDS, XCD-aware remap ----------
// Block remap: b -> xcd=b&7, s=b>>3, col_t=s%col_tiles, lr=s/col_tiles,
// row_t = xcd*rows_per_xcd + lr. All col-tiles of a row-tile land on ONE XCD
// (assuming round-robin block->XCD dispatch), so x rows are fetched into that
// XCD's L2 once and reused by the col-tiles.
__global__ __launch_bounds__(256, 3) void k_gemm1_v3(
    const void* __restrict__ X, const bf16* __restrict__ W1T,
    bf16* __restrict__ h1c, int c0, int C, const int* __restrict__ flags,
    int col_tiles, int rows_per_xcd, int n_row_tiles) {
    const int b = blockIdx.x;
    const int xcd = b & 7;
    const int s = b >> 3;
    const int col_t = s % col_tiles;
    const int lr = s / col_tiles;
    const int row_t = xcd * rows_per_xcd + lr;
    if (row_t >= n_row_tiles) return;

    __shared__ bf16 As[128 * 64];
    __shared__ bf16 Bs[128 * 64];
    const int tid = threadIdx.x;
    const int wave = tid >> 6, lane = tid & 63;
    const int row0 = row_t * 128;
    const int gc0 = c0 + col_t * 128;
    const int isb = flags[0];

    float4v acc[2][8];
#pragma unroll
    for (int i = 0; i < 2; i++)
#pragma unroll
        for (int j = 0; j < 8; j++) acc[i][j] = (float4v){0.f, 0.f, 0.f, 0.f};

    const int rb = wave * 32;
    const int frow = lane & 15;
    const int fk = lane >> 4;

    for (int k0 = 0; k0 < DFEAT; k0 += 64) {
        __syncthreads();
        if (isb) {
            const bf16* xb = (const bf16*)X;
#pragma unroll
            for (int t = 0; t < 4; ++t) {
                int g8 = wave * 4 + t;
                int r = g8 * 8 + (lane >> 3);
                int gr = row0 + r; if (gr >= NNODES) gr = NNODES - 1;
                int ck = (lane & 7) ^ (r & 7);
                load_lds16(xb + (size_t)gr * DFEAT + k0 + ck * 8, &As[g8 * 8 * 64]);
            }
        } else {
            const float* xf = (const float*)X;
            for (int i = tid; i < 128 * 8; i += 256) {
                int r = i >> 3, p = i & 7;
                int gr = row0 + r; if (gr >= NNODES) gr = NNODES - 1;
                int ck = p ^ (r & 7);
                const float* src = xf + (size_t)gr * DFEAT + k0 + ck * 8;
#pragma unroll
                for (int e = 0; e < 8; ++e)
                    As[r * 64 + p * 8 + e] = __float2bfloat16(src[e]);
            }
        }
#pragma unroll
        for (int t = 0; t < 4; ++t) {
            int g8 = wave * 4 + t;
            int cl = g8 * 8 + (lane >> 3);
            int ck = (lane & 7) ^ (cl & 7);
            load_lds16(W1T + (size_t)(gc0 + cl) * DFEAT + k0 + ck * 8, &Bs[g8 * 8 * 64]);
        }
        __syncthreads();
#pragma unroll
        for (int ki = 0; ki < 2; ++ki) {
            const int cc = ki * 4 + fk;
            short8 a[2], b8[8];
#pragma unroll
            for (int i = 0; i < 2; i++) {
                int r = rb + i * 16 + frow;
                a[i] = *(const short8*)&As[r * 64 + (cc ^ (r & 7)) * 8];
            }
#pragma unroll
            for (int j = 0; j < 8; j++) {
                int cl = j * 16 + frow;
                b8[j] = *(const short8*)&Bs[cl * 64 + (cc ^ (cl & 7)) * 8];
            }
#pragma unroll
            for (int i = 0; i < 2; i++)
#pragma unroll
                for (int j = 0; j < 8; j++)
                    acc[i][j] = __builtin_amdgcn_mfma_f32_16x16x32_bf16(a[i], b8[j], acc[i][j], 0, 0, 0);
        }
    }
    const int ccol = gc0 - c0;
#pragma unroll
    for (int i = 0; i < 2; i++) {
#pragma unroll
        for (int r = 0; r < 4; r++) {
            int grow = row0 + rb + i * 16 + (lane >> 4) * 4 + r;
            if (grow < NNODES) {
#pragma unroll
                for (int j = 0; j < 8; j++)
                    h1c[(size_t)grow * C + ccol + j * 16 + (lane & 15)] =
                        __float2bfloat16(acc[i][j][r]);
            }
        }
    }
}

// ---------------- legacy GEMM1 (C==64 fallback) ----------------
__global__ __launch_bounds__(256) void k_gemm1_mfma(
    const void* __restrict__ X, const bf16* __restrict__ W1T,
    bf16* __restrict__ h1c, int c0, int C, const int* __restrict__ flags) {
    __shared__ bf16 As[128 * 64];
    __shared__ bf16 Bs[64 * 64];
    const int tid = threadIdx.x;
    const int wave = tid >> 6, lane = tid & 63;
    const int row0 = blockIdx.x * 128;
    const int gc0 = c0 + blockIdx.y * 64;
    const int isb = flags[0];
    float4v acc[2][4];
#pragma unroll
    for (int i = 0; i < 2; i++)
#pragma unroll
        for (int j = 0; j < 4; j++) acc[i][j] = (float4v){0.f, 0.f, 0.f, 0.f};
    const int rbase = wave * 32;
    const int fl_row = lane & 15;
    const int fl_k8 = (lane >> 4) * 8;
    for (int k0 = 0; k0 < DFEAT; k0 += 64) {
        __syncthreads();
        if (isb) {
            const bf16* xb = (const bf16*)X;
#pragma unroll
            for (int i = 0; i < 4; ++i) {
                int r = i * 32 + wave * 8;
                int gr = row0 + r + (lane >> 3);
                if (gr >= NNODES) gr = NNODES - 1;
                load_lds16(xb + (size_t)gr * DFEAT + k0 + (lane & 7) * 8, &As[r * 64]);
            }
        } else {
            const float* xf = (const float*)X;
            for (int i = tid; i < 128 * 64; i += 256) {
                int r = i >> 6, c = i & 63;
                int gr = row0 + r;
                if (gr >= NNODES) gr = NNODES - 1;
                As[i] = __float2bfloat16(xf[(size_t)gr * DFEAT + k0 + c]);
            }
        }
#pragma unroll
        for (int i = 0; i < 2; ++i) {
            int r = i * 32 + wave * 8;
            int gn = gc0 + r + (lane >> 3);
            load_lds16(W1T + (size_t)gn * DFEAT + k0 + (lane & 7) * 8, &Bs[r * 64]);
        }
        __syncthreads();
#pragma unroll
        for (int ki = 0; ki < 64; ki += 32) {
            short8 a[2], b[4];
#pragma unroll
            for (int i = 0; i < 2; i++)
                a[i] = *(const short8*)&As[(rbase + i * 16 + fl_row) * 64 + ki + fl_k8];
#pragma unroll
            for (int j = 0; j < 4; j++)
                b[j] = *(const short8*)&Bs[(j * 16 + fl_row) * 64 + ki + fl_k8];
#pragma unroll
            for (int i = 0; i < 2; i++)
#pragma unroll
                for (int j = 0; j < 4; j++)
                    acc[i][j] = __builtin_amdgcn_mfma_f32_16x16x32_bf16(a[i], b[j], acc[i][j], 0, 0, 0);
        }
    }
    const int ccol = blockIdx.y * 64;
#pragma unroll
    for (int i = 0; i < 2; i++) {
#pragma unroll
        for (int r = 0; r < 4; r++) {
            int grow = row0 + rbase + i * 16 + (lane >> 4) * 4 + r;
            if (grow < NNODES) {
#pragma unroll
                for (int j = 0; j < 4; j++)
                    h1c[(size_t)grow * C + ccol + j * 16 + (lane & 15)] =
                        __float2bfloat16(acc[i][j][r]);
            }
        }
    }
}

// ---------------- layer1 aggregation, C=512: one wave per node, uint4 loads ----
__global__ __launch_bounds__(256) void k_agg1_512(const bf16* __restrict__ h1c,
                                                  const int* __restrict__ rowptr,
                                                  const int* __restrict__ csr_src,
                                                  const float* __restrict__ dinv,
                                                  const float* __restrict__ b1c,
                                                  bf16* __restrict__ a1c) {
    int v = blockIdx.x * 4 + (threadIdx.x >> 6);
    int lane = threadIdx.x & 63;
    if (v >= NNODES) return;
    int d8 = lane * 8;
    float dv = dinv[v];
    float s2 = dv * dv;
    uint4 w = *(const uint4*)(h1c + (size_t)v * 512 + d8);
    float a0 = s2 * bfbits_lo(w.x), a1 = s2 * bfbits_hi(w.x);
    float a2 = s2 * bfbits_lo(w.y), a3 = s2 * bfbits_hi(w.y);
    float a4 = s2 * bfbits_lo(w.z), a5 = s2 * bfbits_hi(w.z);
    float a6 = s2 * bfbits_lo(w.w), a7 = s2 * bfbits_hi(w.w);
    int pend = rowptr[v + 1];
    for (int p = rowptr[v]; p < pend; ++p) {
        int u = csr_src[p];
        float nw = dinv[u] * dv;
        uint4 q = *(const uint4*)(h1c + (size_t)u * 512 + d8);
        a0 += nw * bfbits_lo(q.x); a1 += nw * bfbits_hi(q.x);
        a2 += nw * bfbits_lo(q.y); a3 += nw * bfbits_hi(q.y);
        a4 += nw * bfbits_lo(q.z); a5 += nw * bfbits_hi(q.z);
        a6 += nw * bfbits_lo(q.w); a7 += nw * bfbits_hi(q.w);
    }
    const float* bb = b1c + d8;
    a0 += bb[0]; a1 += bb[1]; a2 += bb[2]; a3 += bb[3];
    a4 += bb[4]; a5 += bb[5]; a6 += bb[6]; a7 += bb[7];
    bf16 o[8];
    o[0] = __float2bfloat16(a0 > 0.f ? a0 : 0.f);
    o[1] = __float2bfloat16(a1 > 0.f ? a1 : 0.f);
    o[2] = __float2bfloat16(a2 > 0.f ? a2 : 0.f);
    o[3] = __float2bfloat16(a3 > 0.f ? a3 : 0.f);
    o[4] = __float2bfloat16(a4 > 0.f ? a4 : 0.f);
    o[5] = __float2bfloat16(a5 > 0.f ? a5 : 0.f);
    o[6] = __float2bfloat16(a6 > 0.f ? a6 : 0.f);
    o[7] = __float2bfloat16(a7 > 0.f ? a7 : 0.f);
    *(uint4*)(a1c + (size_t)v * 512 + d8) = *(uint4*)o;
}

// ---------------- layer1 aggregation, generic ----------------
__global__ __launch_bounds__(256) void k_agg1(const bf16* __restrict__ h1c,
                                              const int* __restrict__ rowptr,
                                              const int* __restrict__ csr_src,
                                              const float* __restrict__ dinv,
                                              const float* __restrict__ b1c, int c0, int C,
                                              bf16* __restrict__ a1c) {
    const int tshift = (C == 512) ? 7 : (C == 256) ? 6 : (C == 128) ? 5 : 4;
    long long gt = (long long)blockIdx.x * 256 + threadIdx.x;
    int v = (int)(gt >> tshift);
    int d4 = (int)((gt & ((1 << tshift) - 1)) << 2);
    if (v >= NNODES) return;
    float dv = dinv[v];
    uint2 w = *(const uint2*)(h1c + (size_t)v * C + d4);
    float s2 = dv * dv;
    float a0 = s2 * bfbits_lo(w.x), a1 = s2 * bfbits_hi(w.x);
    float a2 = s2 * bfbits_lo(w.y), a3 = s2 * bfbits_hi(w.y);
    int pend = rowptr[v + 1];
    for (int p = rowptr[v]; p < pend; ++p) {
        int u = csr_src[p];
        float nw = dinv[u] * dv;
        uint2 q = *(const uint2*)(h1c + (size_t)u * C + d4);
        a0 += nw * bfbits_lo(q.x); a1 += nw * bfbits_hi(q.x);
        a2 += nw * bfbits_lo(q.y); a3 += nw * bfbits_hi(q.y);
    }
    const float* bb = b1c + c0 + d4;
    a0 += bb[0]; a1 += bb[1]; a2 += bb[2]; a3 += bb[3];
    bf16 o[4];
    o[0] = __float2bfloat16(a0 > 0.f ? a0 : 0.f);
    o[1] = __float2bfloat16(a1 > 0.f ? a1 : 0.f);
    o[2] = __float2bfloat16(a2 > 0.f ? a2 : 0.f);
    o[3] = __float2bfloat16(a3 > 0.f ? a3 : 0.f);
    *(uint2*)(a1c + (size_t)v * C + d4) = *(uint2*)o;
}

// ---------------- GEMM2 MFMA: h2[:, 0:47] (+)= a1c @ W2T^T ----------------
__global__ __launch_bounds__(256) void k_gemm2_mfma(
    const bf16* __restrict__ A, int C, const bf16* __restrict__ W2T, int kg0,
    float* __restrict__ h2, int accum) {
    __shared__ bf16 As[128 * 64];
    __shared__ bf16 Bs[64 * 64];
    const int tid = threadIdx.x;
    const int wave = tid >> 6, lane = tid & 63;
    const int row0 = blockIdx.x * 128;
    float4v acc[2][4];
#pragma unroll
    for (int i = 0; i < 2; i++)
#pragma unroll
        for (int j = 0; j < 4; j++) acc[i][j] = (float4v){0.f, 0.f, 0.f, 0.f};
    const int rbase = wave * 32;
    const int fl_row = lane & 15;
    const int fl_k8 = (lane >> 4) * 8;
    for (int kk = 0; kk < C; kk += 64) {
        __syncthreads();
#pragma unroll
        for (int i = 0; i < 4; ++i) {
            int r = i * 32 + wave * 8;
            int gr = row0 + r + (lane >> 3);
            if (gr >= NNODES) gr = NNODES - 1;
            load_lds16(A + (size_t)gr * C + kk + (lane & 7) * 8, &As[r * 64]);
        }
#pragma unroll
        for (int i = 0; i < 2; ++i) {
            int r = i * 32 + wave * 8;
            int gn = r + (lane >> 3);
            load_lds16(W2T + (size_t)gn * HID + kg0 + kk + (lane & 7) * 8, &Bs[r * 64]);
        }
        __syncthreads();
#pragma unroll
        for (int ki = 0; ki < 64; ki += 32) {
            short8 a[2], b[4];
#pragma unroll
            for (int i = 0; i < 2; i++)
                a[i] = *(const short8*)&As[(rbase + i * 16 + fl_row) * 64 + ki + fl_k8];
#pragma unroll
            for (int j = 0; j < 4; j++)
                b[j] = *(const short8*)&Bs[(j * 16 + fl_row) * 64 + ki + fl_k8];
#pragma unroll
            for (int i = 0; i < 2; i++)
#pragma unroll
                for (int j = 0; j < 4; j++)
                    acc[i][j] = __builtin_amdgcn_mfma_f32_16x16x32_bf16(a[i], b[j], acc[i][j], 0, 0, 0);
        }
    }
#pragma unroll
    for (int i = 0; i < 2; i++) {
#pragma unroll
        for (int r = 0; r < 4; r++) {
            int grow = row0 + rbase + i * 16 + (lane >> 4) * 4 + r;
            if (grow < NNODES) {
#pragma unroll
                for (int j = 0; j < 4; j++) {
                    int col = j * 16 + (lane & 15);
                    if (col < NCLS) {
                        size_t o = (size_t)grow * NCLS + col;
                        h2[o] = accum ? h2[o] + acc[i][j][r] : acc[i][j][r];
                    }
                }
            }
        }
    }
}

// ---------------- layer2 aggregation + bias -> out ----------------
__global__ __launch_bounds__(256) void k_agg2(const float* __restrict__ h2,
                                              const int* __restrict__ rowptr,
                                              const int* __restrict__ csr_src,
                                              const float* __restrict__ dinv,
                                              const float* __restrict__ b2c,
                                              void* out, const int* flags) {
    int v = blockIdx.x * 4 + (threadIdx.x >> 6);
    int d = threadIdx.x & 63;
    if (v >= NNODES || d >= NCLS) return;
    float dv = dinv[v];
    float acc = dv * dv * h2[(size_t)v * NCLS + d];
    int pend = rowptr[v + 1];
    for (int p = rowptr[v]; p < pend; ++p) {
        int u = csr_src[p];
        acc += dinv[u] * dv * h2[(size_t)u * NCLS + d];
    }
    acc += b2c[d];
    size_t o = (size_t)v * NCLS + d;
    if (flags[0]) ((bf16*)out)[o] = __float2bfloat16(acc);
    else          ((float*)out)[o] = acc;
}

extern "C" void kernel_launch(void* const* d_in, const int* in_sizes, int n_in,
                              void* d_out, int out_size, void* d_ws, size_t ws_size,
                              hipStream_t stream) {
    const void* x  = d_in[0];
    const void* ei = d_in[1];
    const void* W1 = d_in[2];
    const void* b1 = d_in[3];
    const void* W2 = d_in[4];
    const void* b2 = d_in[5];

    char* base = (char*)d_ws;
    auto alloc = [&](size_t bytes) -> char* {
        char* p = base;
        base += (bytes + 255) & ~(size_t)255;
        return p;
    };
    int*   flags  = (int*)alloc(64);
    int*   cnt    = (int*)alloc(sizeof(int) * NNODES);
    int*   part   = (int*)alloc(sizeof(int) * 256);
    int*   rowptr = (int*)alloc(sizeof(int) * (NNODES + 1));
    int*   cursor = (int*)alloc(sizeof(int) * NNODES);
    int*   csr    = (int*)alloc(sizeof(int) * NEDGES);
    float* dinv   = (float*)alloc(sizeof(float) * NNODES);
    bf16*  W1T    = (bf16*)alloc(sizeof(bf16) * DFEAT * HID);
    float* b1c    = (float*)alloc(sizeof(float) * HID);
    bf16*  W2T    = (bf16*)alloc(sizeof(bf16) * 64 * HID);
    float* b2c    = (float*)alloc(sizeof(float) * 64);
    float* h2     = (float*)alloc(sizeof(float) * (size_t)NNODES * NCLS);

    size_t used = (size_t)(base - (char*)d_ws);
    size_t rem = (ws_size > used) ? ws_size - used : 0;
    int C = 64;
    if (rem >= (size_t)200000 * 512 + 1024) C = 512;
    else if (rem >= (size_t)200000 * 256 + 1024) C = 256;
    else if (rem >= (size_t)200000 * 128 + 1024) C = 128;
    bf16* h1c = (bf16*)alloc(sizeof(bf16) * (size_t)NNODES * C);
    bf16* a1c = (bf16*)alloc(sizeof(bf16) * (size_t)NNODES * C);

    k_detect<<<1, 64, 0, stream>>>(x, ei, flags);
    k_zero32<<<(NNODES + 255) / 256, 256, 0, stream>>>((unsigned int*)cnt, NNODES);

    k_cvt_w1t<<<(DFEAT * HID + 255) / 256, 256, 0, stream>>>(W1, W1T, flags);
    k_cvt<<<(HID + 255) / 256, 256, 0, stream>>>(b1, b1c, HID, flags);
    k_cvt_w2t<<<(64 * HID + 255) / 256, 256, 0, stream>>>(W2, W2T, flags);
    k_cvt<<<1, 64, 0, stream>>>(b2, b2c, NCLS, flags);

    k_count<<<(NEDGES + 255) / 256, 256, 0, stream>>>(ei, cnt, flags);
    k_dinv<<<(NNODES + 255) / 256, 256, 0, stream>>>(cnt, dinv);
    const int nsb = (NNODES + 255) / 256;  // 196
    k_scan_part<<<nsb, 256, 0, stream>>>(cnt, part);
    k_scan_off<<<1, 256, 0, stream>>>(part, nsb);
    k_scan_fin<<<nsb, 256, 0, stream>>>(cnt, part, rowptr, cursor);
    k_fill<<<(NEDGES + 255) / 256, 256, 0, stream>>>(ei, cursor, csr, flags);

    const int rowblocks = (NNODES + 127) / 128;  // 391
    const int rows_per_xcd = (rowblocks + 7) / 8;  // 49
    int chunk_i = 0;
    for (int c0 = 0; c0 < HID; c0 += C, ++chunk_i) {
        if (C >= 128) {
            int col_tiles = C / 128;
            int nblk = 8 * rows_per_xcd * col_tiles;
            k_gemm1_v3<<<nblk, 256, 0, stream>>>(x, W1T, h1c, c0, C, flags,
                                                 col_tiles, rows_per_xcd, rowblocks);
        } else {
            dim3 g1(rowblocks, 1);
            k_gemm1_mfma<<<g1, 256, 0, stream>>>(x, W1T, h1c, c0, C, flags);
        }
        if (C == 512) {
            k_agg1_512<<<(NNODES + 3) / 4, 256, 0, stream>>>(h1c, rowptr, csr, dinv, b1c, a1c);
        } else {
            size_t nthr = (size_t)NNODES * (C / 4);
            k_agg1<<<(int)((nthr + 255) / 256), 256, 0, stream>>>(h1c, rowptr, csr, dinv, b1c, c0, C, a1c);
        }
        k_gemm2_mfma<<<rowblocks, 256, 0, stream>>>(a1c, C, W2T, c0, h2, chunk_i > 0 ? 1 : 0);
    }

    k_agg2<<<(NNODES + 3) / 4, 256, 0, stream>>>(h2, rowptr, csr, dinv, b2c, d_out, flags);
}